// Round 5
// baseline (1018.741 us; speedup 1.0000x reference)
//
// v12: v11 + occupancy-heuristic pin. v11's launch_bounds(1024,4) set only a
// MIN waves/EU; LLVM's LDS heuristic (58.9KB -> 2 WGs fit in 160KB) targeted
// 8 waves/EU and capped VGPR at 64 anyway -> ~60 spilled regs/lane (VGPR=64
// in rocprof, dur unchanged 680us). Fix: amdgpu_waves_per_eu(4,4) pins the
// target (cap 128), plus LDS padded to 84KB so even the LDS heuristic says
// 1 block/CU (grid=256=1/CU makes the 2nd block unusable anyway).
#include <hip/hip_runtime.h>

typedef unsigned short u16;
typedef unsigned int   u32;
typedef unsigned char  u8;
typedef __attribute__((ext_vector_type(8))) short          short8;
typedef __attribute__((ext_vector_type(8))) unsigned short ushort8;
typedef __attribute__((ext_vector_type(4))) float          f32x4;

#define MFMA(a,b,c) __builtin_amdgcn_mfma_f32_16x16x32_bf16((a),(b),(c),0,0,0)
#define Nx 2048
#define Dx 1024
#define SCALEx 0.125f

__device__ __forceinline__ float bf2f(u16 u){ u32 x=((u32)u)<<16; return __builtin_bit_cast(float,x); }
__device__ __forceinline__ u16 f2bf(float f){ u32 u=__builtin_bit_cast(u32,f); u32 r=(u+0x7FFFu+((u>>16)&1u))>>16; return (u16)r; }
__device__ __forceinline__ short8 lds8(const u16* p){ return *(const short8*)p; }

// ---- dtype normalization (identity if already bf16) ----
__device__ int looks_bf16_dev(const u16* p, int nsamp, float lo, float hi){
  int cnt = 0;
  for (int i = 0; i < nsamp; ++i){
    float a = fabsf(bf2f(p[2*i]));
    if (a >= lo && a <= hi) cnt++;
  }
  return (2*cnt > nsamp) ? 1 : 0;
}

__global__ __launch_bounds__(256) void conv_w(const void* __restrict__ in, u16* __restrict__ S,
                                              int n, int nsamp, float lo, float hi){
  __shared__ int flag;
  if (threadIdx.x == 0) flag = looks_bf16_dev((const u16*)in, nsamp, lo, hi);
  __syncthreads();
  const int isbf = flag;
  int i = blockIdx.x*256 + threadIdx.x;
  int stride = gridDim.x*256;
  if (isbf){
    const u16* pu = (const u16*)in;
    for (; i < n; i += stride) S[i] = pu[i];
  } else {
    const float* pf = (const float*)in;
    for (; i < n; i += stride) S[i] = f2bf(pf[i]);
  }
}

__global__ __launch_bounds__(256) void copyb(const u16* __restrict__ S, u16* __restrict__ dst, int n){
  int i = blockIdx.x*256 + threadIdx.x;
  int stride = gridDim.x*256;
  for (; i < n; i += stride) dst[i] = S[i];
}

__global__ void conv_small(void* buf, int n, float lo, float hi){
  __shared__ float tmp[64];
  __shared__ int flag;
  int t = threadIdx.x;
  if (t == 0) flag = looks_bf16_dev((const u16*)buf, n/2, lo, hi);
  __syncthreads();
  if (t < n) tmp[t] = flag ? bf2f(((const u16*)buf)[t]) : ((const float*)buf)[t];
  __syncthreads();
  if (t < n) ((u16*)buf)[t] = f2bf(tmp[t]);
}

// ---------------------------------------------------------------------------
// NT GEMM bf16: C[M][ldc] = A[M][1024] @ Bt[N][1024]^T
// ---------------------------------------------------------------------------
__global__ __launch_bounds__(256) void gemm_bf16(
    const u16* __restrict__ A, const u16* __restrict__ Bt, u16* __restrict__ C, int ldc)
{
  const int tid = threadIdx.x;
  const int lane = tid & 63, wave = tid >> 6;
  const int wm = wave >> 1, wn = wave & 1;
  const int l15 = lane & 15, quad = lane >> 4;
  const int m0 = blockIdx.y * 128, n0 = blockIdx.x * 128;
  __shared__ u16 As[128*32], Bs[128*32];
  f32x4 acc[4][4] = {};
  const int srow0 = tid >> 2, scol = tid & 3;
  const int srow1 = (tid + 256) >> 2;
  for (int k0 = 0; k0 < 1024; k0 += 32) {
    ushort8 a0 = *(const ushort8*)&A [(size_t)(m0 + srow0)*1024 + k0 + scol*8];
    ushort8 b0 = *(const ushort8*)&Bt[(size_t)(n0 + srow0)*1024 + k0 + scol*8];
    ushort8 a1 = *(const ushort8*)&A [(size_t)(m0 + srow1)*1024 + k0 + scol*8];
    ushort8 b1 = *(const ushort8*)&Bt[(size_t)(n0 + srow1)*1024 + k0 + scol*8];
    __syncthreads();
    *(ushort8*)&As[srow0*32 + scol*8] = a0;
    *(ushort8*)&Bs[srow0*32 + scol*8] = b0;
    *(ushort8*)&As[srow1*32 + scol*8] = a1;
    *(ushort8*)&Bs[srow1*32 + scol*8] = b1;
    __syncthreads();
    short8 af[4], bfr[4];
    #pragma unroll
    for (int i = 0; i < 4; ++i) af[i]  = lds8(&As[(wm*64 + i*16 + l15)*32 + quad*8]);
    #pragma unroll
    for (int j = 0; j < 4; ++j) bfr[j] = lds8(&Bs[(wn*64 + j*16 + l15)*32 + quad*8]);
    #pragma unroll
    for (int i = 0; i < 4; ++i)
      #pragma unroll
      for (int j = 0; j < 4; ++j)
        acc[i][j] = MFMA(af[i], bfr[j], acc[i][j]);
  }
  const int q4 = quad*4;
  #pragma unroll
  for (int i = 0; i < 4; ++i)
    #pragma unroll
    for (int j = 0; j < 4; ++j)
      #pragma unroll
      for (int r = 0; r < 4; ++r)
        C[(size_t)(m0 + wm*64 + i*16 + q4 + r)*ldc + n0 + wn*64 + j*16 + l15]
          = f2bf(acc[i][j][r]);
}

// ---------------------------------------------------------------------------
// transpose bf16: A [2][2048][1024] -> T [2][1024][2048], 64x64 tiles
// ---------------------------------------------------------------------------
__global__ __launch_bounds__(256) void transp(const u16* __restrict__ A, u16* __restrict__ T)
{
  __shared__ u16 tl[64*68];
  const int m0 = blockIdx.x*64, d0 = blockIdx.y*64;
  const size_t ab = (size_t)blockIdx.z * Nx * Dx;
  const size_t tb = (size_t)blockIdx.z * Dx * Nx;
  const int t = threadIdx.x;
  const int r = t >> 3, c8 = (t & 7)*8;
  *(short8*)&tl[r*68 + c8]      = *(const short8*)&A[ab + (size_t)(m0+r)*Dx + d0 + c8];
  *(short8*)&tl[(r+32)*68 + c8] = *(const short8*)&A[ab + (size_t)(m0+r+32)*Dx + d0 + c8];
  __syncthreads();
  ushort8 o0, o1;
  #pragma unroll
  for (int j = 0; j < 8; ++j){
    o0[j] = tl[(c8+j)*68 + r];
    o1[j] = tl[(c8+j)*68 + r + 32];
  }
  *(ushort8*)&T[tb + (size_t)(d0+r)*Nx + m0 + c8]      = o0;
  *(ushort8*)&T[tb + (size_t)(d0+r+32)*Nx + m0 + c8]   = o1;
}

// ---------------------------------------------------------------------------
// attn2: 256 blocks x 1024 thr; wave c == head c; 16 q rows/block; 32-key
// tiles. Pass1: per-lane online stats, no LDS/barriers. Pass2: 2 barriers/iter
// (cross-wave PS reduce only); V^T and x^T B-frags direct from global.
// LDS padded to 84KB: with 58.9KB the backend's occupancy heuristic targets
// 2 blocks/CU (8 waves/EU) and caps VGPR at 64 -> massive spill. 84KB > 80KB
// forces the 1-block/CU target that the 256-block grid actually delivers.
// ---------------------------------------------------------------------------
#define B_PRT 0        // 16 waves * [16 q][40] u16 = 20480
#define B_PSP 20480    // 16 waves * [16 q][36] f32 = 36864
#define B_PSA 57344    // [16 q][40] u16 = 1280
#define B_DG  58624    // 16 f32
#define B_SZ  86016    // padded to 84KB (occupancy pin)

__global__ __launch_bounds__(1024)
__attribute__((amdgpu_waves_per_eu(4, 4)))
void attn2(
    const u16* __restrict__ x, const u16* __restrict__ wq,
    const u16* __restrict__ wo, const u16* __restrict__ wkwq,
    const u16* __restrict__ wvwo, const u16* __restrict__ K16,
    const u16* __restrict__ Vb0, const u16* __restrict__ Vb1a,
    const u16* __restrict__ Vb1b, const u16* __restrict__ xT,
    float* out)
{
  __shared__ __align__(16) u8 AR[B_SZ];
  const int tid = threadIdx.x;
  const int lane = tid & 63, c = tid >> 6;          // wave == head, 0..15
  const int l15 = lane & 15, quad = lane >> 4, q4 = quad*4;
  int bb = blockIdx.x; bb = (bb & 7)*32 + (bb >> 3); // XCD swizzle (256 = 8*32)
  const int b = bb >> 7, n0 = (bb & 127) * 16;
  const size_t xbase = (size_t)b * Nx * Dx;
  const u16* xxt = (const u16*)out;                  // bf16 XXT [2][2048][2048]
  const size_t xxbase = (size_t)b * Nx * Nx;

  u16*   prt = (u16*)(AR + B_PRT);
  float* psp = (float*)(AR + B_PSP);
  u16*   psa = (u16*)(AR + B_PSA);
  float* dgv = (float*)(AR + B_DG);
  u16*   qrt = (u16*)(AR + 0) + c*(16*72);           // prologue overlay

  const float L2E = 1.4426950408889634f;

  // ---- prologue: Q (this head's 64 cols), scaled by SCALE*log2e ----
  {
    f32x4 qacc[4] = {};
    #pragma unroll 1
    for (int kc = 0; kc < 32; ++kc) {
      short8 af = *(const short8*)&x[xbase + (size_t)(n0 + l15)*Dx + kc*32 + quad*8];
      #pragma unroll
      for (int j = 0; j < 4; ++j) {
        short8 bf = *(const short8*)&wq[(size_t)(c*64 + j*16 + l15)*Dx + kc*32 + quad*8];
        qacc[j] = MFMA(af, bf, qacc[j]);
      }
    }
    const float qs = SCALEx * L2E;
    #pragma unroll
    for (int j = 0; j < 4; ++j)
      #pragma unroll
      for (int r = 0; r < 4; ++r)
        qrt[(q4+r)*72 + j*16 + l15] = f2bf(qacc[j][r] * qs);
  }
  // ---- prologue: exact diag(x x^T), wave c -> row n0+c ----
  {
    float s = 0.f;
    #pragma unroll
    for (int p = 0; p < 2; ++p) {
      short8 v = *(const short8*)&x[xbase + (size_t)(n0+c)*Dx + p*512 + lane*8];
      #pragma unroll
      for (int i = 0; i < 8; ++i){ float f = bf2f((u16)v[i]); s += f*f; }
    }
    #pragma unroll
    for (int o = 1; o < 64; o <<= 1) s += __shfl_xor(s, o);
    if (lane == 0) dgv[c] = s;
  }
  short8 qf[2];
  #pragma unroll
  for (int s = 0; s < 2; ++s) qf[s] = lds8(&qrt[l15*72 + s*32 + quad*8]);
  __syncthreads();
  float dv[4];
  #pragma unroll
  for (int r = 0; r < 4; ++r) dv[r] = dgv[q4+r];
  __syncthreads();                                   // qrt region released

  const float wkh = bf2f(wkwq[c]) * L2E;             // log2 domain
  const float wvh = bf2f(wvwo[c]);

  // ---- pass 1: per-lane online stats (lane's keys: m = 16s+l15 mod 32) ----
  float mrun[4], lrun[4];
  #pragma unroll
  for (int r = 0; r < 4; ++r){ mrun[r] = -1e30f; lrun[r] = 0.f; }

  const u16* pk  = K16 + xbase + (size_t)l15*Dx + c*64;
  const u16* pxx = xxt + xxbase + (size_t)(n0+q4)*Nx + l15;

  #pragma unroll 2
  for (int mt = 0; mt < 64; ++mt) {
    float xb[2][4];
    #pragma unroll
    for (int s = 0; s < 2; ++s)
      #pragma unroll
      for (int r = 0; r < 4; ++r)
        xb[s][r] = bf2f(pxx[r*Nx + s*16]);
    short8 kf[2][2];
    #pragma unroll
    for (int s = 0; s < 2; ++s)
      #pragma unroll
      for (int k2 = 0; k2 < 2; ++k2)
        kf[s][k2] = *(const short8*)&pk[s*16*Dx + k2*32 + quad*8];
    f32x4 t2[2];
    #pragma unroll
    for (int s = 0; s < 2; ++s){
      f32x4 t = {};
      t = MFMA(qf[0], kf[s][0], t);
      t = MFMA(qf[1], kf[s][1], t);
      t2[s] = t;
    }
    const int kb = mt*32 + l15;
    #pragma unroll
    for (int r = 0; r < 4; ++r){
      const int ng = n0 + q4 + r;
      float b0 = (kb      == ng) ? dv[r] : xb[0][r];
      float b1 = (kb + 16 == ng) ? dv[r] : xb[1][r];
      float sv0 = t2[0][r] + wkh*b0;
      float sv1 = t2[1][r] + wkh*b1;
      float m2 = fmaxf(sv0, sv1);
      float mn = fmaxf(mrun[r], m2);
      lrun[r] = lrun[r]*exp2f(mrun[r]-mn) + exp2f(sv0-mn) + exp2f(sv1-mn);
      mrun[r] = mn;
    }
    pk += 32*Dx; pxx += 32;
  }
  float ms[4], il[4];
  #pragma unroll
  for (int r = 0; r < 4; ++r){
    float mr = mrun[r];
    #pragma unroll
    for (int o = 1; o < 16; o <<= 1) mr = fmaxf(mr, __shfl_xor(mr, o));
    float ls = lrun[r]*exp2f(mrun[r]-mr);
    #pragma unroll
    for (int o = 1; o < 16; o <<= 1) ls += __shfl_xor(ls, o);
    ms[r] = mr; il[r] = 1.0f/fmaxf(ls, 1e-30f);
  }

  // ---- pass 2 ----
  f32x4 O[4] = {}, U[4] = {};
  const u16* vbp; int voff;
  if (b == 0){ vbp = Vb0; voff = 0; }
  else if (c < 8){ vbp = Vb1a; voff = 0; }
  else { vbp = Vb1b; voff = 512; }
  const u16* pv  = vbp + (size_t)(c*64 - voff + l15)*Nx;
  const u16* pxt = xT + (size_t)b*Dx*Nx + (size_t)(c*64 + l15)*Nx;
  pk  = K16 + xbase + (size_t)l15*Dx + c*64;
  pxx = xxt + xxbase + (size_t)(n0+q4)*Nx + l15;

  #pragma unroll 1
  for (int mt = 0; mt < 64; ++mt) {
    float xb[2][4];
    #pragma unroll
    for (int s = 0; s < 2; ++s)
      #pragma unroll
      for (int r = 0; r < 4; ++r)
        xb[s][r] = bf2f(pxx[r*Nx + s*16]);
    short8 kf[2][2];
    #pragma unroll
    for (int s = 0; s < 2; ++s)
      #pragma unroll
      for (int k2 = 0; k2 < 2; ++k2)
        kf[s][k2] = *(const short8*)&pk[s*16*Dx + k2*32 + quad*8];
    short8 vf[4], xf[4];
    #pragma unroll
    for (int dt = 0; dt < 4; ++dt){
      vf[dt] = *(const short8*)&pv [dt*16*Nx + quad*8];
      xf[dt] = *(const short8*)&pxt[dt*16*Nx + quad*8];
    }
    f32x4 t2[2];
    #pragma unroll
    for (int s = 0; s < 2; ++s){
      f32x4 t = {};
      t = MFMA(qf[0], kf[s][0], t);
      t = MFMA(qf[1], kf[s][1], t);
      t2[s] = t;
    }
    const int kb = mt*32 + l15;
    #pragma unroll
    for (int s = 0; s < 2; ++s)
      #pragma unroll
      for (int r = 0; r < 4; ++r){
        const int ng = n0 + q4 + r;
        float bias = (kb + s*16 == ng) ? dv[r] : xb[s][r];
        float sv = t2[s][r] + wkh*bias;
        float p = exp2f(fminf(sv - ms[r], 0.f)) * il[r];
        prt[c*640 + (q4+r)*40 + s*16 + l15] = f2bf(p);
        psp[c*576 + (q4+r)*36 + s*16 + l15] = wvh * p;
      }
    // PV (prt wave-private)
    short8 pf = lds8(&prt[c*640 + l15*40 + quad*8]);
    #pragma unroll
    for (int dt = 0; dt < 4; ++dt) O[dt] = MFMA(pf, vf[dt], O[dt]);
    __syncthreads();                                 // psp ready
    if (tid < 512){
      const int qq = tid >> 5, mm = tid & 31;
      float v = 0.f;
      #pragma unroll
      for (int w = 0; w < 16; ++w) v += psp[w*576 + qq*36 + mm];
      psa[qq*40 + mm] = f2bf(v);
    }
    __syncthreads();                                 // psa ready
    short8 psf = lds8(&psa[l15*40 + quad*8]);
    #pragma unroll
    for (int ct = 0; ct < 4; ++ct) U[ct] = MFMA(psf, xf[ct], U[ct]);
    pk += 32*Dx; pxx += 32; pv += 32; pxt += 32;
  }

  // ---- epilogue: U += O @ wo^T, fp32 store ----
  __syncthreads();
  u16* ol = (u16*)(AR + 0);                          // [16 q][1040] u16
  #pragma unroll
  for (int dt = 0; dt < 4; ++dt)
    #pragma unroll
    for (int r = 0; r < 4; ++r)
      ol[(q4+r)*1040 + c*64 + dt*16 + l15] = f2bf(O[dt][r]);
  __syncthreads();
  #pragma unroll 1
  for (int kc = 0; kc < 32; ++kc){
    short8 af = lds8(&ol[l15*1040 + kc*32 + quad*8]);
    #pragma unroll
    for (int ct = 0; ct < 4; ++ct){
      short8 bw = *(const short8*)&wo[(size_t)(c*64 + ct*16 + l15)*Dx + kc*32 + quad*8];
      U[ct] = MFMA(af, bw, U[ct]);
    }
  }
  #pragma unroll
  for (int ct = 0; ct < 4; ++ct)
    #pragma unroll
    for (int r = 0; r < 4; ++r)
      out[xbase + (size_t)(n0+q4+r)*Dx + c*64 + ct*16 + l15] = U[ct][r];
}

// ---------------------------------------------------------------------------
// attn_k: v9 fallback (used only if ws_size < 8MB) — verified path.
// ---------------------------------------------------------------------------
#define L_XMT 0
#define L_PRT 81920
#define L_PSP 102400
#define L_PSA 120832
#define L_DG  122112
#define L_SZ  122176

__global__ __launch_bounds__(512) void attn_k(
    const u16* __restrict__ x, const u16* __restrict__ wq,
    const u16* __restrict__ wo, const u16* __restrict__ wkwq,
    const u16* __restrict__ wvwo, const u16* __restrict__ K16,
    const u16* __restrict__ Vb0, const u16* __restrict__ Vb1a,
    const u16* __restrict__ Vb1b, float* out)
{
  __shared__ __align__(16) u8 AR[L_SZ];
  const int tid = threadIdx.x;
  const int lane = tid & 63, c = tid >> 6;
  const int l15 = lane & 15, quad = lane >> 4, q4 = quad*4;
  const int bb = blockIdx.x;
  const int b = bb >> 7, n0 = (bb & 127) * 16;
  const size_t xbase = (size_t)b * Nx * Dx;
  const u16* xxt = (const u16*)out;
  const size_t xxbase = (size_t)b * Nx * Nx;

  u16*   xmt = (u16*)(AR + L_XMT) + c * (128*40);
  u16*   qrt = (u16*)(AR + L_XMT) + c * (16*136);
  u16*   prt = (u16*)(AR + L_PRT);
  float* psp = (float*)(AR + L_PSP);
  u16*   psa = (u16*)(AR + L_PSA);
  float* dgv = (float*)(AR + L_DG);

  {
    f32x4 qacc[8] = {};
    #pragma unroll 1
    for (int kc = 0; kc < 32; ++kc) {
      short8 af = *(const short8*)&x[xbase + (size_t)(n0 + l15)*Dx + kc*32 + quad*8];
      #pragma unroll
      for (int j = 0; j < 8; ++j) {
        short8 bf = *(const short8*)&wq[(size_t)(c*128 + j*16 + l15)*Dx + kc*32 + quad*8];
        qacc[j] = MFMA(af, bf, qacc[j]);
      }
    }
    #pragma unroll
    for (int j = 0; j < 8; ++j)
      #pragma unroll
      for (int r = 0; r < 4; ++r)
        qrt[(q4+r)*136 + j*16 + l15] = f2bf(qacc[j][r]);
  }
  {
    int row = 2*c + (lane >> 5);
    int ch = lane & 31;
    float s = 0.f;
    #pragma unroll
    for (int p = 0; p < 4; ++p) {
      short8 v = *(const short8*)&x[xbase + (size_t)(n0+row)*Dx + p*256 + ch*8];
      #pragma unroll
      for (int i = 0; i < 8; ++i) { float f = bf2f((u16)v[i]); s += f*f; }
    }
    #pragma unroll
    for (int o = 1; o < 32; o <<= 1) s += __shfl_xor(s, o);
    if ((lane & 31) == 0) dgv[row] = s;
  }
  __syncthreads();
  short8 qf[2][2];
  #pragma unroll
  for (int hh = 0; hh < 2; ++hh)
    #pragma unroll
    for (int s = 0; s < 2; ++s)
      qf[hh][s] = lds8(&qrt[l15*136 + hh*64 + s*32 + quad*8]);
  float dv[4];
  #pragma unroll
  for (int r = 0; r < 4; ++r) dv[r] = dgv[q4+r];
  __syncthreads();

  float wkh[2], wvh[2];
  #pragma unroll
  for (int hh = 0; hh < 2; ++hh){ wkh[hh] = bf2f(wkwq[c*2+hh]); wvh[hh] = bf2f(wvwo[c*2+hh]); }

  float mrun[2][4], lrun[2][4];
  #pragma unroll
  for (int hh=0;hh<2;++hh)
    #pragma unroll
    for (int r=0;r<4;++r){ mrun[hh][r] = -1e30f; lrun[hh][r] = 0.f; }

  #pragma unroll 1
  for (int mt = 0; mt < 64; ++mt) {
    u16 xb[2][4];
    #pragma unroll
    for (int s=0;s<2;++s)
      #pragma unroll
      for (int r=0;r<4;++r)
        xb[s][r] = xxt[xxbase + (size_t)(n0+q4+r)*Nx + mt*32 + s*16 + l15];
    short8 kf[2][2][2];
    #pragma unroll
    for (int hh=0;hh<2;++hh)
      #pragma unroll
      for (int s=0;s<2;++s)
        #pragma unroll
        for (int k2=0;k2<2;++k2)
          kf[hh][s][k2] = *(const short8*)&K16[xbase + (size_t)(mt*32+s*16+l15)*Dx + (c*2+hh)*64 + k2*32 + quad*8];
    f32x4 t2[2][2];
    #pragma unroll
    for (int hh=0;hh<2;++hh)
      #pragma unroll
      for (int s=0;s<2;++s){
        f32x4 t = {};
        t = MFMA(qf[hh][0], kf[hh][s][0], t);
        t = MFMA(qf[hh][1], kf[hh][s][1], t);
        t2[hh][s] = t;
      }
    #pragma unroll
    for (int hh=0;hh<2;++hh)
      #pragma unroll
      for (int r=0;r<4;++r){
        const int ng = n0 + q4 + r;
        float b0 = (mt*32      + l15 == ng) ? dv[r] : bf2f(xb[0][r]);
        float b1 = (mt*32 + 16 + l15 == ng) ? dv[r] : bf2f(xb[1][r]);
        float sv0 = SCALEx*t2[hh][0][r] + wkh[hh]*b0;
        float sv1 = SCALEx*t2[hh][1][r] + wkh[hh]*b1;
        float mx = fmaxf(sv0, sv1);
        #pragma unroll
        for (int o=1;o<16;o<<=1) mx = fmaxf(mx, __shfl_xor(mx, o));
        float mnew = fmaxf(mrun[hh][r], mx);
        float e = __expf(fminf(sv0-mnew,0.f)) + __expf(fminf(sv1-mnew,0.f));
        #pragma unroll
        for (int o=1;o<16;o<<=1) e += __shfl_xor(e, o);
        lrun[hh][r] = lrun[hh][r]*__expf(fminf(mrun[hh][r]-mnew,0.f)) + e;
        mrun[hh][r] = mnew;
      }
  }
  float ms[2][4], il[2][4];
  #pragma unroll
  for (int hh=0;hh<2;++hh)
    #pragma unroll
    for (int r=0;r<4;++r){ ms[hh][r] = mrun[hh][r]; il[hh][r] = 1.0f/fmaxf(lrun[hh][r],1e-30f); }

  f32x4 O[2][4] = {};
  f32x4 U[8] = {};
  const u16* vb = (b == 0) ? Vb0 : ((c < 4) ? Vb1a : Vb1b);
  const int dof = (b == 1 && c >= 4) ? 512 : 0;

  #pragma unroll 1
  for (int mt = 0; mt < 64; ++mt) {
    u16 xb[2][4];
    #pragma unroll
    for (int s=0;s<2;++s)
      #pragma unroll
      for (int r=0;r<4;++r)
        xb[s][r] = xxt[xxbase + (size_t)(n0+q4+r)*Nx + mt*32 + s*16 + l15];
    short8 kf[2][2][2];
    #pragma unroll
    for (int hh=0;hh<2;++hh)
      #pragma unroll
      for (int s=0;s<2;++s)
        #pragma unroll
        for (int k2=0;k2<2;++k2)
          kf[hh][s][k2] = *(const short8*)&K16[xbase + (size_t)(mt*32+s*16+l15)*Dx + (c*2+hh)*64 + k2*32 + quad*8];
    short8 vf[2][4];
    #pragma unroll
    for (int hh=0;hh<2;++hh)
      #pragma unroll
      for (int dt=0;dt<4;++dt)
        vf[hh][dt] = *(const short8*)&vb[(size_t)((c*2+hh)*64 + dt*16 + l15 - dof)*Nx + mt*32 + quad*8];
    short8 a0[4], a1[4];
    #pragma unroll
    for (int i=0;i<4;++i){
      int m2 = (lane >> 4)*2 + i*8;
      a0[i] = *(const short8*)&x[xbase + (size_t)(mt*32 + m2    )*Dx + c*128 + l15*8];
      a1[i] = *(const short8*)&x[xbase + (size_t)(mt*32 + m2 + 1)*Dx + c*128 + l15*8];
    }
    f32x4 t2[2][2];
    #pragma unroll
    for (int hh=0;hh<2;++hh)
      #pragma unroll
      for (int s=0;s<2;++s){
        f32x4 t = {};
        t = MFMA(qf[hh][0], kf[hh][s][0], t);
        t = MFMA(qf[hh][1], kf[hh][s][1], t);
        t2[hh][s] = t;
      }
    float ps_[2][4] = {};
    #pragma unroll
    for (int hh=0;hh<2;++hh)
      #pragma unroll
      for (int s=0;s<2;++s)
        #pragma unroll
        for (int r=0;r<4;++r){
          const int ng = n0 + q4 + r;
          float bias = (mt*32 + s*16 + l15 == ng) ? dv[r] : bf2f(xb[s][r]);
          float sv = SCALEx*t2[hh][s][r] + wkh[hh]*bias;
          float p = __expf(fminf(sv - ms[hh][r], 0.f)) * il[hh][r];
          prt[(c*2+hh)*640 + (q4+r)*40 + s*16 + l15] = f2bf(p);
          ps_[s][r] += wvh[hh]*p;
        }
    #pragma unroll
    for (int s=0;s<2;++s)
      #pragma unroll
      for (int r=0;r<4;++r)
        psp[c*576 + (q4+r)*36 + s*16 + l15] = ps_[s][r];
    #pragma unroll
    for (int i=0;i<4;++i){
      int m2 = (lane >> 4)*2 + i*8;
      int sw = (l15 & 3) << 3;
      #pragma unroll
      for (int j=0;j<8;++j){
        int dl = l15*8 + j;
        *(u32*)&xmt[dl*40 + (m2 ^ sw)] = (u32)(u16)a0[i][j] | ((u32)(u16)a1[i][j] << 16);
      }
    }
    #pragma unroll
    for (int hh=0; hh<2; ++hh){
      short8 pf = lds8(&prt[(c*2+hh)*640 + l15*40 + quad*8]);
      #pragma unroll
      for (int dt=0;dt<4;++dt)
        O[hh][dt] = MFMA(pf, vf[hh][dt], O[hh][dt]);
    }
    __syncthreads();
    {
      float v = 0.f;
      #pragma unroll
      for (int w=0;w<8;++w) v += psp[w*576 + (tid>>5)*36 + (tid&31)];
      psa[(tid>>5)*40 + (tid&31)] = f2bf(v);
    }
    __syncthreads();
    short8 psf = lds8(&psa[l15*40 + quad*8]);
    #pragma unroll
    for (int ct=0;ct<8;++ct){
      int d = ct*16 + l15;
      int sw = ((d >> 3) & 3) << 3;
      short8 xf = lds8(&xmt[d*40 + ((quad*8) ^ sw)]);
      U[ct] = MFMA(psf, xf, U[ct]);
    }
  }

  __syncthreads();
  u16* ol = (u16*)(AR + L_XMT);
  #pragma unroll
  for (int hh=0;hh<2;++hh)
    #pragma unroll
    for (int dt=0;dt<4;++dt)
      #pragma unroll
      for (int r=0;r<4;++r)
        ol[(q4+r)*1040 + (c*2+hh)*64 + dt*16 + l15] = f2bf(O[hh][dt][r]);
  __syncthreads();
  #pragma unroll 1
  for (int kc=0; kc<32; ++kc){
    short8 af = lds8(&ol[l15*1040 + kc*32 + quad*8]);
    #pragma unroll
    for (int ct=0;ct<8;++ct){
      short8 bfw = *(const short8*)&wo[(size_t)(c*128 + ct*16 + l15)*Dx + kc*32 + quad*8];
      U[ct] = MFMA(af, bfw, U[ct]);
    }
  }
  #pragma unroll
  for (int ct=0; ct<8; ++ct)
    #pragma unroll
    for (int r=0;r<4;++r)
      out[xbase + (size_t)(n0+q4+r)*Dx + c*128 + ct*16 + l15] = U[ct][r];
}

// ---------------------------------------------------------------------------
extern "C" void kernel_launch(void* const* d_in, const int* in_sizes, int n_in,
                              void* d_out, int out_size, void* d_ws, size_t ws_size,
                              hipStream_t stream) {
  u16* x16   = (u16*)d_in[0];
  u16* K16   = x16 + 4u*1024u*1024u;
  u16* wqk16 = (u16*)d_in[1];
  u16* Vb0   = wqk16 + 2u*1024u*1024u;
  u16* wv16  = (u16*)d_in[2];
  u16* Vb1a  = wv16 + 1024u*1024u;
  u16* wo16  = (u16*)d_in[3];
  u16* Vb1b  = wo16 + 1024u*1024u;
  float* outF = (float*)d_out;
  u16* S = (u16*)d_out;

  const float loW = 0.000244140625f, hiW = 0.25f;
  conv_w<<<dim3(512), 256, 0, stream>>>(d_in[0], S, 4*1024*1024, 512, 0.00390625f, 16.0f);
  copyb <<<dim3(512), 256, 0, stream>>>(S, x16, 4*1024*1024);
  conv_w<<<dim3(256), 256, 0, stream>>>(d_in[1], S, 2*1024*1024, 512, loW, hiW);
  copyb <<<dim3(256), 256, 0, stream>>>(S, wqk16, 2*1024*1024);
  conv_w<<<dim3(128), 256, 0, stream>>>(d_in[2], S, 1024*1024, 512, loW, hiW);
  copyb <<<dim3(128), 256, 0, stream>>>(S, wv16, 1024*1024);
  conv_w<<<dim3(128), 256, 0, stream>>>(d_in[3], S, 1024*1024, 512, loW, hiW);
  copyb <<<dim3(128), 256, 0, stream>>>(S, wo16, 1024*1024);
  conv_small<<<dim3(1), 64, 0, stream>>>((void*)d_in[4], 16, loW, hiW);
  conv_small<<<dim3(1), 64, 0, stream>>>((void*)d_in[5], 16, loW, hiW);

  const size_t xt_bytes = (size_t)2*1024*2048*2;
  const bool useXT = (d_ws != nullptr) && (ws_size >= xt_bytes);
  u16* xT = (u16*)d_ws;

  if (useXT)
    transp<<<dim3(32, 16, 2), 256, 0, stream>>>(x16, xT);

  // K = x @ wk^T (both batches)
  gemm_bf16<<<dim3(8, 32), 256, 0, stream>>>(x16, wqk16 + 1024u*1024u, K16, 1024);
  // V^T = wv @ x^T
  gemm_bf16<<<dim3(16, 8), 256, 0, stream>>>(wv16, x16, Vb0, 2048);
  gemm_bf16<<<dim3(16, 4), 256, 0, stream>>>(wv16,              x16 + 2048u*1024u, Vb1a, 2048);
  gemm_bf16<<<dim3(16, 4), 256, 0, stream>>>(wv16 + 512u*1024u, x16 + 2048u*1024u, Vb1b, 2048);
  // XXT = x @ x^T (bf16) into d_out
  gemm_bf16<<<dim3(16, 16), 256, 0, stream>>>(x16,               x16,               (u16*)d_out,                  2048);
  gemm_bf16<<<dim3(16, 16), 256, 0, stream>>>(x16 + 2048u*1024u, x16 + 2048u*1024u, (u16*)d_out + 4u*1024u*1024u, 2048);

  if (useXT)
    attn2<<<dim3(256), 1024, 0, stream>>>(x16, wqk16, wo16,
        (const u16*)d_in[4], (const u16*)d_in[5], K16, Vb0, Vb1a, Vb1b, xT, outF);
  else
    attn_k<<<dim3(256), 512, 0, stream>>>(x16, wqk16, wo16,
        (const u16*)d_in[4], (const u16*)d_in[5], K16, Vb0, Vb1a, Vb1b, outF);
}

// Round 6
// 948.878 us; speedup vs baseline: 1.0736x; 1.0736x over previous
//
// v13: restructure — U moved OUT of the attention inner loop. attn2 now only
// does QK+softmax+PV and writes the head-summed PSA (bf16, [2][2048][2048]) to
// d_ws; "out += PSA @ x" runs afterward as a tiled NN GEMM (gemm_nn_add, C+=).
// Rationale (r5 post-mortem): 1024-thr blocks cap the unified VGPR budget at
// 128/lane (4 waves/EU minimum); the old loop's ~20 loads + 12 MFMA operands
// forced serialization (arch VGPR pinned at 64, dur flat 677-681 across all
// knob changes). Removing xf loads/U-MFMAs/psa roundtrip/1 barrier fits the
// budget. psp double-buffered bf16 -> 1 barrier/iter. transp/xT deleted.
// Fallback: ws < 16MB -> verified v9 attn_k.
#include <hip/hip_runtime.h>

typedef unsigned short u16;
typedef unsigned int   u32;
typedef unsigned char  u8;
typedef __attribute__((ext_vector_type(8))) short          short8;
typedef __attribute__((ext_vector_type(8))) unsigned short ushort8;
typedef __attribute__((ext_vector_type(4))) float          f32x4;

#define MFMA(a,b,c) __builtin_amdgcn_mfma_f32_16x16x32_bf16((a),(b),(c),0,0,0)
#define Nx 2048
#define Dx 1024
#define SCALEx 0.125f

__device__ __forceinline__ float bf2f(u16 u){ u32 x=((u32)u)<<16; return __builtin_bit_cast(float,x); }
__device__ __forceinline__ u16 f2bf(float f){ u32 u=__builtin_bit_cast(u32,f); u32 r=(u+0x7FFFu+((u>>16)&1u))>>16; return (u16)r; }
__device__ __forceinline__ short8 lds8(const u16* p){ return *(const short8*)p; }

// ---- dtype normalization (identity if already bf16) ----
__device__ int looks_bf16_dev(const u16* p, int nsamp, float lo, float hi){
  int cnt = 0;
  for (int i = 0; i < nsamp; ++i){
    float a = fabsf(bf2f(p[2*i]));
    if (a >= lo && a <= hi) cnt++;
  }
  return (2*cnt > nsamp) ? 1 : 0;
}

__global__ __launch_bounds__(256) void conv_w(const void* __restrict__ in, u16* __restrict__ S,
                                              int n, int nsamp, float lo, float hi){
  __shared__ int flag;
  if (threadIdx.x == 0) flag = looks_bf16_dev((const u16*)in, nsamp, lo, hi);
  __syncthreads();
  const int isbf = flag;
  int i = blockIdx.x*256 + threadIdx.x;
  int stride = gridDim.x*256;
  if (isbf){
    const u16* pu = (const u16*)in;
    for (; i < n; i += stride) S[i] = pu[i];
  } else {
    const float* pf = (const float*)in;
    for (; i < n; i += stride) S[i] = f2bf(pf[i]);
  }
}

__global__ __launch_bounds__(256) void copyb(const u16* __restrict__ S, u16* __restrict__ dst, int n){
  int i = blockIdx.x*256 + threadIdx.x;
  int stride = gridDim.x*256;
  for (; i < n; i += stride) dst[i] = S[i];
}

__global__ void conv_small(void* buf, int n, float lo, float hi){
  __shared__ float tmp[64];
  __shared__ int flag;
  int t = threadIdx.x;
  if (t == 0) flag = looks_bf16_dev((const u16*)buf, n/2, lo, hi);
  __syncthreads();
  if (t < n) tmp[t] = flag ? bf2f(((const u16*)buf)[t]) : ((const float*)buf)[t];
  __syncthreads();
  if (t < n) ((u16*)buf)[t] = f2bf(tmp[t]);
}

// ---------------------------------------------------------------------------
// NT GEMM bf16: C[M][ldc] = A[M][1024] @ Bt[N][1024]^T
// ---------------------------------------------------------------------------
__global__ __launch_bounds__(256) void gemm_bf16(
    const u16* __restrict__ A, const u16* __restrict__ Bt, u16* __restrict__ C, int ldc)
{
  const int tid = threadIdx.x;
  const int lane = tid & 63, wave = tid >> 6;
  const int wm = wave >> 1, wn = wave & 1;
  const int l15 = lane & 15, quad = lane >> 4;
  const int m0 = blockIdx.y * 128, n0 = blockIdx.x * 128;
  __shared__ u16 As[128*32], Bs[128*32];
  f32x4 acc[4][4] = {};
  const int srow0 = tid >> 2, scol = tid & 3;
  const int srow1 = (tid + 256) >> 2;
  for (int k0 = 0; k0 < 1024; k0 += 32) {
    ushort8 a0 = *(const ushort8*)&A [(size_t)(m0 + srow0)*1024 + k0 + scol*8];
    ushort8 b0 = *(const ushort8*)&Bt[(size_t)(n0 + srow0)*1024 + k0 + scol*8];
    ushort8 a1 = *(const ushort8*)&A [(size_t)(m0 + srow1)*1024 + k0 + scol*8];
    ushort8 b1 = *(const ushort8*)&Bt[(size_t)(n0 + srow1)*1024 + k0 + scol*8];
    __syncthreads();
    *(ushort8*)&As[srow0*32 + scol*8] = a0;
    *(ushort8*)&Bs[srow0*32 + scol*8] = b0;
    *(ushort8*)&As[srow1*32 + scol*8] = a1;
    *(ushort8*)&Bs[srow1*32 + scol*8] = b1;
    __syncthreads();
    short8 af[4], bfr[4];
    #pragma unroll
    for (int i = 0; i < 4; ++i) af[i]  = lds8(&As[(wm*64 + i*16 + l15)*32 + quad*8]);
    #pragma unroll
    for (int j = 0; j < 4; ++j) bfr[j] = lds8(&Bs[(wn*64 + j*16 + l15)*32 + quad*8]);
    #pragma unroll
    for (int i = 0; i < 4; ++i)
      #pragma unroll
      for (int j = 0; j < 4; ++j)
        acc[i][j] = MFMA(af[i], bfr[j], acc[i][j]);
  }
  const int q4 = quad*4;
  #pragma unroll
  for (int i = 0; i < 4; ++i)
    #pragma unroll
    for (int j = 0; j < 4; ++j)
      #pragma unroll
      for (int r = 0; r < 4; ++r)
        C[(size_t)(m0 + wm*64 + i*16 + q4 + r)*ldc + n0 + wn*64 + j*16 + l15]
          = f2bf(acc[i][j][r]);
}

// ---------------------------------------------------------------------------
// NN GEMM bf16 with fp32 accumulate-into-C:
// C[M][1024] += A[M][2048] @ B[2048][1024]   (per-batch via blockIdx.z)
// B staged transposed into LDS ([n][k], u32 k-pair packing, XOR slot swizzle).
// ---------------------------------------------------------------------------
__global__ __launch_bounds__(256) void gemm_nn_add(
    const u16* __restrict__ A0, const u16* __restrict__ B0, float* __restrict__ C0)
{
  const int tid = threadIdx.x;
  const int lane = tid & 63, wave = tid >> 6;
  const int wm = wave >> 1, wn = wave & 1;
  const int l15 = lane & 15, quad = lane >> 4;
  const int m0 = blockIdx.y * 128, n0 = blockIdx.x * 128;
  const u16* A = A0 + (size_t)blockIdx.z * Nx * Nx;
  const u16* B = B0 + (size_t)blockIdx.z * Nx * Dx;
  float*     C = C0 + (size_t)blockIdx.z * Nx * Dx;
  __shared__ u16 As[128*32];
  __shared__ u16 Bs[128*40];                // [n 0..127][k-pairs, 20 u32, padded]
  f32x4 acc[4][4] = {};
  const int srow0 = tid >> 2, scol = tid & 3;
  const int srow1 = (tid + 256) >> 2;
  const int kp  = tid >> 4;                 // 0..15 (k-pair row)
  const int nc8 = (tid & 15) * 8;           // n col8 base
  for (int k0 = 0; k0 < Nx; k0 += 32) {
    ushort8 a0 = *(const ushort8*)&A[(size_t)(m0 + srow0)*Nx + k0 + scol*8];
    ushort8 a1 = *(const ushort8*)&A[(size_t)(m0 + srow1)*Nx + k0 + scol*8];
    ushort8 b0 = *(const ushort8*)&B[(size_t)(k0 + 2*kp    )*Dx + n0 + nc8];
    ushort8 b1 = *(const ushort8*)&B[(size_t)(k0 + 2*kp + 1)*Dx + n0 + nc8];
    __syncthreads();
    *(ushort8*)&As[srow0*32 + scol*8] = a0;
    *(ushort8*)&As[srow1*32 + scol*8] = a1;
    #pragma unroll
    for (int j = 0; j < 8; ++j){
      int n = nc8 + j;
      int slot = kp ^ (((n >> 3) & 3) << 2);     // XOR swizzle (bank spread)
      *(u32*)&Bs[n*40 + slot*2] = (u32)(u16)b0[j] | ((u32)(u16)b1[j] << 16);
    }
    __syncthreads();
    short8 af[4], bfr[4];
    #pragma unroll
    for (int i = 0; i < 4; ++i) af[i] = lds8(&As[(wm*64 + i*16 + l15)*32 + quad*8]);
    #pragma unroll
    for (int j = 0; j < 4; ++j){
      int n = wn*64 + j*16 + l15;
      int q2 = quad ^ ((n >> 3) & 3);            // inverse swizzle
      bfr[j] = lds8(&Bs[n*40 + q2*8]);
    }
    #pragma unroll
    for (int i = 0; i < 4; ++i)
      #pragma unroll
      for (int j = 0; j < 4; ++j)
        acc[i][j] = MFMA(af[i], bfr[j], acc[i][j]);
  }
  const int q4 = quad*4;
  #pragma unroll
  for (int i = 0; i < 4; ++i)
    #pragma unroll
    for (int j = 0; j < 4; ++j)
      #pragma unroll
      for (int r = 0; r < 4; ++r){
        size_t idx = (size_t)(m0 + wm*64 + i*16 + q4 + r)*Dx + n0 + wn*64 + j*16 + l15;
        C[idx] += acc[i][j][r];
      }
}

// ---------------------------------------------------------------------------
// attn2: 256 blocks x 1024 thr; wave c == head c; 16 q rows/block; 32-key
// tiles. Pass1: per-lane online stats, no LDS/barriers. Pass2: QK+softmax+PV
// + head-sum PSA write to GLOBAL (d_ws); psp double-buffered bf16 -> exactly
// ONE barrier per iteration. No U/xf/psa-MFMA machinery (-> fits 128-reg cap).
// ---------------------------------------------------------------------------
#define B_PRT 0        // 16 waves * [16 q][40] u16 = 20480
#define B_PSP 20480    // 2 bufs * 16 waves * [16 q][40] u16 = 40960
#define B_DG  61440    // 16 f32
#define B_SZ  86016    // padded (occupancy pin: 1 block/CU)

__global__ __launch_bounds__(1024)
__attribute__((amdgpu_waves_per_eu(4, 4)))
void attn2(
    const u16* __restrict__ x, const u16* __restrict__ wq,
    const u16* __restrict__ wo, const u16* __restrict__ wkwq,
    const u16* __restrict__ wvwo, const u16* __restrict__ K16,
    const u16* __restrict__ Vb0, const u16* __restrict__ Vb1a,
    const u16* __restrict__ Vb1b, u16* __restrict__ PSA,
    float* out)
{
  __shared__ __align__(16) u8 AR[B_SZ];
  const int tid = threadIdx.x;
  const int lane = tid & 63, c = tid >> 6;          // wave == head, 0..15
  const int l15 = lane & 15, quad = lane >> 4, q4 = quad*4;
  int bb = blockIdx.x; bb = (bb & 7)*32 + (bb >> 3); // XCD swizzle (256 = 8*32)
  const int b = bb >> 7, n0 = (bb & 127) * 16;
  const size_t xbase = (size_t)b * Nx * Dx;
  const u16* xxt = (const u16*)out;                  // bf16 XXT [2][2048][2048]
  const size_t xxbase = (size_t)b * Nx * Nx;
  u16* psag = PSA + (size_t)b * Nx * Nx;

  u16*   prt = (u16*)(AR + B_PRT);
  u16*   psp = (u16*)(AR + B_PSP);                   // 2 x [16w][16q][40m] bf16
  float* dgv = (float*)(AR + B_DG);
  u16*   qrt = (u16*)(AR + 0) + c*(16*72);           // prologue overlay

  const float L2E = 1.4426950408889634f;

  // ---- prologue: Q (this head's 64 cols), scaled by SCALE*log2e ----
  {
    f32x4 qacc[4] = {};
    #pragma unroll 1
    for (int kc = 0; kc < 32; ++kc) {
      short8 af = *(const short8*)&x[xbase + (size_t)(n0 + l15)*Dx + kc*32 + quad*8];
      #pragma unroll
      for (int j = 0; j < 4; ++j) {
        short8 bf = *(const short8*)&wq[(size_t)(c*64 + j*16 + l15)*Dx + kc*32 + quad*8];
        qacc[j] = MFMA(af, bf, qacc[j]);
      }
    }
    const float qs = SCALEx * L2E;
    #pragma unroll
    for (int j = 0; j < 4; ++j)
      #pragma unroll
      for (int r = 0; r < 4; ++r)
        qrt[(q4+r)*72 + j*16 + l15] = f2bf(qacc[j][r] * qs);
  }
  // ---- prologue: exact diag(x x^T), wave c -> row n0+c ----
  {
    float s = 0.f;
    #pragma unroll
    for (int p = 0; p < 2; ++p) {
      short8 v = *(const short8*)&x[xbase + (size_t)(n0+c)*Dx + p*512 + lane*8];
      #pragma unroll
      for (int i = 0; i < 8; ++i){ float f = bf2f((u16)v[i]); s += f*f; }
    }
    #pragma unroll
    for (int o = 1; o < 64; o <<= 1) s += __shfl_xor(s, o);
    if (lane == 0) dgv[c] = s;
  }
  short8 qf[2];
  #pragma unroll
  for (int s = 0; s < 2; ++s) qf[s] = lds8(&qrt[l15*72 + s*32 + quad*8]);
  __syncthreads();
  float dv[4];
  #pragma unroll
  for (int r = 0; r < 4; ++r) dv[r] = dgv[q4+r];
  __syncthreads();                                   // qrt region released

  const float wkh = bf2f(wkwq[c]) * L2E;             // log2 domain
  const float wvh = bf2f(wvwo[c]);

  // ---- pass 1: per-lane online stats (lane's keys: m = 16s+l15 mod 32) ----
  float mrun[4], lrun[4];
  #pragma unroll
  for (int r = 0; r < 4; ++r){ mrun[r] = -1e30f; lrun[r] = 0.f; }

  const u16* pk  = K16 + xbase + (size_t)l15*Dx + c*64;
  const u16* pxx = xxt + xxbase + (size_t)(n0+q4)*Nx + l15;

  #pragma unroll 2
  for (int mt = 0; mt < 64; ++mt) {
    float xb[2][4];
    #pragma unroll
    for (int s = 0; s < 2; ++s)
      #pragma unroll
      for (int r = 0; r < 4; ++r)
        xb[s][r] = bf2f(pxx[r*Nx + s*16]);
    short8 kf[2][2];
    #pragma unroll
    for (int s = 0; s < 2; ++s)
      #pragma unroll
      for (int k2 = 0; k2 < 2; ++k2)
        kf[s][k2] = *(const short8*)&pk[s*16*Dx + k2*32 + quad*8];
    f32x4 t2[2];
    #pragma unroll
    for (int s = 0; s < 2; ++s){
      f32x4 t = {};
      t = MFMA(qf[0], kf[s][0], t);
      t = MFMA(qf[1], kf[s][1], t);
      t2[s] = t;
    }
    const int kb = mt*32 + l15;
    #pragma unroll
    for (int r = 0; r < 4; ++r){
      const int ng = n0 + q4 + r;
      float b0 = (kb      == ng) ? dv[r] : xb[0][r];
      float b1 = (kb + 16 == ng) ? dv[r] : xb[1][r];
      float sv0 = t2[0][r] + wkh*b0;
      float sv1 = t2[1][r] + wkh*b1;
      float m2 = fmaxf(sv0, sv1);
      float mn = fmaxf(mrun[r], m2);
      lrun[r] = lrun[r]*exp2f(mrun[r]-mn) + exp2f(sv0-mn) + exp2f(sv1-mn);
      mrun[r] = mn;
    }
    pk += 32*Dx; pxx += 32;
  }
  float ms[4], il[4];
  #pragma unroll
  for (int r = 0; r < 4; ++r){
    float mr = mrun[r];
    #pragma unroll
    for (int o = 1; o < 16; o <<= 1) mr = fmaxf(mr, __shfl_xor(mr, o));
    float ls = lrun[r]*exp2f(mrun[r]-mr);
    #pragma unroll
    for (int o = 1; o < 16; o <<= 1) ls += __shfl_xor(ls, o);
    ms[r] = mr; il[r] = 1.0f/fmaxf(ls, 1e-30f);
  }

  // ---- pass 2: O (per-head PV) + PSA (head-sum) to global ----
  f32x4 O[4] = {};
  const u16* vbp; int voff;
  if (b == 0){ vbp = Vb0; voff = 0; }
  else if (c < 8){ vbp = Vb1a; voff = 0; }
  else { vbp = Vb1b; voff = 512; }
  const u16* pv = vbp + (size_t)(c*64 - voff + l15)*Nx;
  pk  = K16 + xbase + (size_t)l15*Dx + c*64;
  pxx = xxt + xxbase + (size_t)(n0+q4)*Nx + l15;

  #pragma unroll 1
  for (int mt = 0; mt < 64; ++mt) {
    float xb[2][4];
    #pragma unroll
    for (int s = 0; s < 2; ++s)
      #pragma unroll
      for (int r = 0; r < 4; ++r)
        xb[s][r] = bf2f(pxx[r*Nx + s*16]);
    short8 kf[2][2];
    #pragma unroll
    for (int s = 0; s < 2; ++s)
      #pragma unroll
      for (int k2 = 0; k2 < 2; ++k2)
        kf[s][k2] = *(const short8*)&pk[s*16*Dx + k2*32 + quad*8];
    short8 vf[4];
    #pragma unroll
    for (int dt = 0; dt < 4; ++dt)
      vf[dt] = *(const short8*)&pv[dt*16*Nx + quad*8];
    f32x4 t2[2];
    #pragma unroll
    for (int s = 0; s < 2; ++s){
      f32x4 t = {};
      t = MFMA(qf[0], kf[s][0], t);
      t = MFMA(qf[1], kf[s][1], t);
      t2[s] = t;
    }
    const int kb = mt*32 + l15;
    u16* pspw = psp + (mt & 1)*10240;
    #pragma unroll
    for (int s = 0; s < 2; ++s)
      #pragma unroll
      for (int r = 0; r < 4; ++r){
        const int ng = n0 + q4 + r;
        float bias = (kb + s*16 == ng) ? dv[r] : xb[s][r];
        float sv = t2[s][r] + wkh*bias;
        float p = exp2f(fminf(sv - ms[r], 0.f)) * il[r];
        prt[c*640 + (q4+r)*40 + s*16 + l15] = f2bf(p);
        pspw[c*640 + (q4+r)*40 + s*16 + l15] = f2bf(wvh * p);
      }
    // PV (prt wave-private)
    short8 pf = lds8(&prt[c*640 + l15*40 + quad*8]);
    #pragma unroll
    for (int dt = 0; dt < 4; ++dt) O[dt] = MFMA(pf, vf[dt], O[dt]);
    __syncthreads();                                 // psp[mt&1] ready
    if (tid < 512){
      const int qq = tid >> 5, mm = tid & 31;
      float v = 0.f;
      #pragma unroll
      for (int w = 0; w < 16; ++w) v += bf2f(pspw[w*640 + qq*40 + mm]);
      psag[(size_t)(n0 + qq)*Nx + mt*32 + mm] = f2bf(v);
    }
    pk += 32*Dx; pxx += 32; pv += 32;
  }

  // ---- epilogue: Uo = O @ wo^T, fp32 store (PSA@x added by gemm_nn_add) ----
  __syncthreads();
  u16* ol = (u16*)(AR + 0);                          // [16 q][1040] u16
  #pragma unroll
  for (int dt = 0; dt < 4; ++dt)
    #pragma unroll
    for (int r = 0; r < 4; ++r)
      ol[(q4+r)*1040 + c*64 + dt*16 + l15] = f2bf(O[dt][r]);
  __syncthreads();
  f32x4 Uo[4] = {};
  #pragma unroll 1
  for (int kc = 0; kc < 32; ++kc){
    short8 af = lds8(&ol[l15*1040 + kc*32 + quad*8]);
    #pragma unroll
    for (int ct = 0; ct < 4; ++ct){
      short8 bw = *(const short8*)&wo[(size_t)(c*64 + ct*16 + l15)*Dx + kc*32 + quad*8];
      Uo[ct] = MFMA(af, bw, Uo[ct]);
    }
  }
  #pragma unroll
  for (int ct = 0; ct < 4; ++ct)
    #pragma unroll
    for (int r = 0; r < 4; ++r)
      out[xbase + (size_t)(n0+q4+r)*Dx + c*64 + ct*16 + l15] = Uo[ct][r];
}

// ---------------------------------------------------------------------------
// attn_k: v9 fallback (used only if ws_size < 16MB) — verified path.
// ---------------------------------------------------------------------------
#define L_XMT 0
#define L_PRT 81920
#define L_PSP 102400
#define L_PSA 120832
#define L_DG  122112
#define L_SZ  122176

__global__ __launch_bounds__(512) void attn_k(
    const u16* __restrict__ x, const u16* __restrict__ wq,
    const u16* __restrict__ wo, const u16* __restrict__ wkwq,
    const u16* __restrict__ wvwo, const u16* __restrict__ K16,
    const u16* __restrict__ Vb0, const u16* __restrict__ Vb1a,
    const u16* __restrict__ Vb1b, float* out)
{
  __shared__ __align__(16) u8 AR[L_SZ];
  const int tid = threadIdx.x;
  const int lane = tid & 63, c = tid >> 6;
  const int l15 = lane & 15, quad = lane >> 4, q4 = quad*4;
  const int bb = blockIdx.x;
  const int b = bb >> 7, n0 = (bb & 127) * 16;
  const size_t xbase = (size_t)b * Nx * Dx;
  const u16* xxt = (const u16*)out;
  const size_t xxbase = (size_t)b * Nx * Nx;

  u16*   xmt = (u16*)(AR + L_XMT) + c * (128*40);
  u16*   qrt = (u16*)(AR + L_XMT) + c * (16*136);
  u16*   prt = (u16*)(AR + L_PRT);
  float* psp = (float*)(AR + L_PSP);
  u16*   psa = (u16*)(AR + L_PSA);
  float* dgv = (float*)(AR + L_DG);

  {
    f32x4 qacc[8] = {};
    #pragma unroll 1
    for (int kc = 0; kc < 32; ++kc) {
      short8 af = *(const short8*)&x[xbase + (size_t)(n0 + l15)*Dx + kc*32 + quad*8];
      #pragma unroll
      for (int j = 0; j < 8; ++j) {
        short8 bf = *(const short8*)&wq[(size_t)(c*128 + j*16 + l15)*Dx + kc*32 + quad*8];
        qacc[j] = MFMA(af, bf, qacc[j]);
      }
    }
    #pragma unroll
    for (int j = 0; j < 8; ++j)
      #pragma unroll
      for (int r = 0; r < 4; ++r)
        qrt[(q4+r)*136 + j*16 + l15] = f2bf(qacc[j][r]);
  }
  {
    int row = 2*c + (lane >> 5);
    int ch = lane & 31;
    float s = 0.f;
    #pragma unroll
    for (int p = 0; p < 4; ++p) {
      short8 v = *(const short8*)&x[xbase + (size_t)(n0+row)*Dx + p*256 + ch*8];
      #pragma unroll
      for (int i = 0; i < 8; ++i) { float f = bf2f((u16)v[i]); s += f*f; }
    }
    #pragma unroll
    for (int o = 1; o < 32; o <<= 1) s += __shfl_xor(s, o);
    if ((lane & 31) == 0) dgv[row] = s;
  }
  __syncthreads();
  short8 qf[2][2];
  #pragma unroll
  for (int hh = 0; hh < 2; ++hh)
    #pragma unroll
    for (int s = 0; s < 2; ++s)
      qf[hh][s] = lds8(&qrt[l15*136 + hh*64 + s*32 + quad*8]);
  float dv[4];
  #pragma unroll
  for (int r = 0; r < 4; ++r) dv[r] = dgv[q4+r];
  __syncthreads();

  float wkh[2], wvh[2];
  #pragma unroll
  for (int hh = 0; hh < 2; ++hh){ wkh[hh] = bf2f(wkwq[c*2+hh]); wvh[hh] = bf2f(wvwo[c*2+hh]); }

  float mrun[2][4], lrun[2][4];
  #pragma unroll
  for (int hh=0;hh<2;++hh)
    #pragma unroll
    for (int r=0;r<4;++r){ mrun[hh][r] = -1e30f; lrun[hh][r] = 0.f; }

  #pragma unroll 1
  for (int mt = 0; mt < 64; ++mt) {
    u16 xb[2][4];
    #pragma unroll
    for (int s=0;s<2;++s)
      #pragma unroll
      for (int r=0;r<4;++r)
        xb[s][r] = xxt[xxbase + (size_t)(n0+q4+r)*Nx + mt*32 + s*16 + l15];
    short8 kf[2][2][2];
    #pragma unroll
    for (int hh=0;hh<2;++hh)
      #pragma unroll
      for (int s=0;s<2;++s)
        #pragma unroll
        for (int k2=0;k2<2;++k2)
          kf[hh][s][k2] = *(const short8*)&K16[xbase + (size_t)(mt*32+s*16+l15)*Dx + (c*2+hh)*64 + k2*32 + quad*8];
    f32x4 t2[2][2];
    #pragma unroll
    for (int hh=0;hh<2;++hh)
      #pragma unroll
      for (int s=0;s<2;++s){
        f32x4 t = {};
        t = MFMA(qf[hh][0], kf[hh][s][0], t);
        t = MFMA(qf[hh][1], kf[hh][s][1], t);
        t2[hh][s] = t;
      }
    #pragma unroll
    for (int hh=0;hh<2;++hh)
      #pragma unroll
      for (int r=0;r<4;++r){
        const int ng = n0 + q4 + r;
        float b0 = (mt*32      + l15 == ng) ? dv[r] : bf2f(xb[0][r]);
        float b1 = (mt*32 + 16 + l15 == ng) ? dv[r] : bf2f(xb[1][r]);
        float sv0 = SCALEx*t2[hh][0][r] + wkh[hh]*b0;
        float sv1 = SCALEx*t2[hh][1][r] + wkh[hh]*b1;
        float mx = fmaxf(sv0, sv1);
        #pragma unroll
        for (int o=1;o<16;o<<=1) mx = fmaxf(mx, __shfl_xor(mx, o));
        float mnew = fmaxf(mrun[hh][r], mx);
        float e = __expf(fminf(sv0-mnew,0.f)) + __expf(fminf(sv1-mnew,0.f));
        #pragma unroll
        for (int o=1;o<16;o<<=1) e += __shfl_xor(e, o);
        lrun[hh][r] = lrun[hh][r]*__expf(fminf(mrun[hh][r]-mnew,0.f)) + e;
        mrun[hh][r] = mnew;
      }
  }
  float ms[2][4], il[2][4];
  #pragma unroll
  for (int hh=0;hh<2;++hh)
    #pragma unroll
    for (int r=0;r<4;++r){ ms[hh][r] = mrun[hh][r]; il[hh][r] = 1.0f/fmaxf(lrun[hh][r],1e-30f); }

  f32x4 O[2][4] = {};
  f32x4 U[8] = {};
  const u16* vb = (b == 0) ? Vb0 : ((c < 4) ? Vb1a : Vb1b);
  const int dof = (b == 1 && c >= 4) ? 512 : 0;

  #pragma unroll 1
  for (int mt = 0; mt < 64; ++mt) {
    u16 xb[2][4];
    #pragma unroll
    for (int s=0;s<2;++s)
      #pragma unroll
      for (int r=0;r<4;++r)
        xb[s][r] = xxt[xxbase + (size_t)(n0+q4+r)*Nx + mt*32 + s*16 + l15];
    short8 kf[2][2][2];
    #pragma unroll
    for (int hh=0;hh<2;++hh)
      #pragma unroll
      for (int s=0;s<2;++s)
        #pragma unroll
        for (int k2=0;k2<2;++k2)
          kf[hh][s][k2] = *(const short8*)&K16[xbase + (size_t)(mt*32+s*16+l15)*Dx + (c*2+hh)*64 + k2*32 + quad*8];
    short8 vf[2][4];
    #pragma unroll
    for (int hh=0;hh<2;++hh)
      #pragma unroll
      for (int dt=0;dt<4;++dt)
        vf[hh][dt] = *(const short8*)&vb[(size_t)((c*2+hh)*64 + dt*16 + l15 - dof)*Nx + mt*32 + quad*8];
    short8 a0[4], a1[4];
    #pragma unroll
    for (int i=0;i<4;++i){
      int m2 = (lane >> 4)*2 + i*8;
      a0[i] = *(const short8*)&x[xbase + (size_t)(mt*32 + m2    )*Dx + c*128 + l15*8];
      a1[i] = *(const short8*)&x[xbase + (size_t)(mt*32 + m2 + 1)*Dx + c*128 + l15*8];
    }
    f32x4 t2[2][2];
    #pragma unroll
    for (int hh=0;hh<2;++hh)
      #pragma unroll
      for (int s=0;s<2;++s){
        f32x4 t = {};
        t = MFMA(qf[hh][0], kf[hh][s][0], t);
        t = MFMA(qf[hh][1], kf[hh][s][1], t);
        t2[hh][s] = t;
      }
    float ps_[2][4] = {};
    #pragma unroll
    for (int hh=0;hh<2;++hh)
      #pragma unroll
      for (int s=0;s<2;++s)
        #pragma unroll
        for (int r=0;r<4;++r){
          const int ng = n0 + q4 + r;
          float bias = (mt*32 + s*16 + l15 == ng) ? dv[r] : bf2f(xb[s][r]);
          float sv = SCALEx*t2[hh][s][r] + wkh[hh]*bias;
          float p = __expf(fminf(sv - ms[hh][r], 0.f)) * il[hh][r];
          prt[(c*2+hh)*640 + (q4+r)*40 + s*16 + l15] = f2bf(p);
          ps_[s][r] += wvh[hh]*p;
        }
    #pragma unroll
    for (int s=0;s<2;++s)
      #pragma unroll
      for (int r=0;r<4;++r)
        psp[c*576 + (q4+r)*36 + s*16 + l15] = ps_[s][r];
    #pragma unroll
    for (int i=0;i<4;++i){
      int m2 = (lane >> 4)*2 + i*8;
      int sw = (l15 & 3) << 3;
      #pragma unroll
      for (int j=0;j<8;++j){
        int dl = l15*8 + j;
        *(u32*)&xmt[dl*40 + (m2 ^ sw)] = (u32)(u16)a0[i][j] | ((u32)(u16)a1[i][j] << 16);
      }
    }
    #pragma unroll
    for (int hh=0; hh<2; ++hh){
      short8 pf = lds8(&prt[(c*2+hh)*640 + l15*40 + quad*8]);
      #pragma unroll
      for (int dt=0;dt<4;++dt)
        O[hh][dt] = MFMA(pf, vf[hh][dt], O[hh][dt]);
    }
    __syncthreads();
    {
      float v = 0.f;
      #pragma unroll
      for (int w=0;w<8;++w) v += psp[w*576 + (tid>>5)*36 + (tid&31)];
      psa[(tid>>5)*40 + (tid&31)] = f2bf(v);
    }
    __syncthreads();
    short8 psf = lds8(&psa[l15*40 + quad*8]);
    #pragma unroll
    for (int ct=0;ct<8;++ct){
      int d = ct*16 + l15;
      int sw = ((d >> 3) & 3) << 3;
      short8 xf = lds8(&xmt[d*40 + ((quad*8) ^ sw)]);
      U[ct] = MFMA(psf, xf, U[ct]);
    }
  }

  __syncthreads();
  u16* ol = (u16*)(AR + L_XMT);
  #pragma unroll
  for (int hh=0;hh<2;++hh)
    #pragma unroll
    for (int dt=0;dt<4;++dt)
      #pragma unroll
      for (int r=0;r<4;++r)
        ol[(q4+r)*1040 + (c*2+hh)*64 + dt*16 + l15] = f2bf(O[hh][dt][r]);
  __syncthreads();
  #pragma unroll 1
  for (int kc=0; kc<32; ++kc){
    short8 af = lds8(&ol[l15*1040 + kc*32 + quad*8]);
    #pragma unroll
    for (int ct=0;ct<8;++ct){
      short8 bfw = *(const short8*)&wo[(size_t)(c*128 + ct*16 + l15)*Dx + kc*32 + quad*8];
      U[ct] = MFMA(af, bfw, U[ct]);
    }
  }
  #pragma unroll
  for (int ct=0; ct<8; ++ct)
    #pragma unroll
    for (int r=0;r<4;++r)
      out[xbase + (size_t)(n0+q4+r)*Dx + c*128 + ct*16 + l15] = U[ct][r];
}

// ---------------------------------------------------------------------------
extern "C" void kernel_launch(void* const* d_in, const int* in_sizes, int n_in,
                              void* d_out, int out_size, void* d_ws, size_t ws_size,
                              hipStream_t stream) {
  u16* x16   = (u16*)d_in[0];
  u16* K16   = x16 + 4u*1024u*1024u;
  u16* wqk16 = (u16*)d_in[1];
  u16* Vb0   = wqk16 + 2u*1024u*1024u;
  u16* wv16  = (u16*)d_in[2];
  u16* Vb1a  = wv16 + 1024u*1024u;
  u16* wo16  = (u16*)d_in[3];
  u16* Vb1b  = wo16 + 1024u*1024u;
  float* outF = (float*)d_out;
  u16* S = (u16*)d_out;

  const float loW = 0.000244140625f, hiW = 0.25f;
  conv_w<<<dim3(512), 256, 0, stream>>>(d_in[0], S, 4*1024*1024, 512, 0.00390625f, 16.0f);
  copyb <<<dim3(512), 256, 0, stream>>>(S, x16, 4*1024*1024);
  conv_w<<<dim3(256), 256, 0, stream>>>(d_in[1], S, 2*1024*1024, 512, loW, hiW);
  copyb <<<dim3(256), 256, 0, stream>>>(S, wqk16, 2*1024*1024);
  conv_w<<<dim3(128), 256, 0, stream>>>(d_in[2], S, 1024*1024, 512, loW, hiW);
  copyb <<<dim3(128), 256, 0, stream>>>(S, wv16, 1024*1024);
  conv_w<<<dim3(128), 256, 0, stream>>>(d_in[3], S, 1024*1024, 512, loW, hiW);
  copyb <<<dim3(128), 256, 0, stream>>>(S, wo16, 1024*1024);
  conv_small<<<dim3(1), 64, 0, stream>>>((void*)d_in[4], 16, loW, hiW);
  conv_small<<<dim3(1), 64, 0, stream>>>((void*)d_in[5], 16, loW, hiW);

  const size_t psa_bytes = (size_t)2*2048*2048*2;   // 16 MB
  const bool usePSA = (d_ws != nullptr) && (ws_size >= psa_bytes);

  // K = x @ wk^T (both batches)
  gemm_bf16<<<dim3(8, 32), 256, 0, stream>>>(x16, wqk16 + 1024u*1024u, K16, 1024);
  // V^T = wv @ x^T
  gemm_bf16<<<dim3(16, 8), 256, 0, stream>>>(wv16, x16, Vb0, 2048);
  gemm_bf16<<<dim3(16, 4), 256, 0, stream>>>(wv16,              x16 + 2048u*1024u, Vb1a, 2048);
  gemm_bf16<<<dim3(16, 4), 256, 0, stream>>>(wv16 + 512u*1024u, x16 + 2048u*1024u, Vb1b, 2048);
  // XXT = x @ x^T (bf16) into d_out
  gemm_bf16<<<dim3(16, 16), 256, 0, stream>>>(x16,               x16,               (u16*)d_out,                  2048);
  gemm_bf16<<<dim3(16, 16), 256, 0, stream>>>(x16 + 2048u*1024u, x16 + 2048u*1024u, (u16*)d_out + 4u*1024u*1024u, 2048);

  if (usePSA) {
    attn2<<<dim3(256), 1024, 0, stream>>>(x16, wqk16, wo16,
        (const u16*)d_in[4], (const u16*)d_in[5], K16, Vb0, Vb1a, Vb1b,
        (u16*)d_ws, outF);
    // out += PSA @ x
    gemm_nn_add<<<dim3(8, 16, 2), 256, 0, stream>>>((const u16*)d_ws, x16, outF);
  } else {
    attn_k<<<dim3(256), 512, 0, stream>>>(x16, wqk16, wo16,
        (const u16*)d_in[4], (const u16*)d_in[5], K16, Vb0, Vb1a, Vb1b, outF);
  }
}

// Round 7
// 936.011 us; speedup vs baseline: 1.0884x; 1.0137x over previous
//
// v14: attention decomposed into independent barrier-free kernels.
// v13 post-mortem: VGPR~60 is genuine demand (no spill); the 16-wave
// mega-block (1 block/CU, barrier+cross-wave reduce every key-tile, 2 full
// K passes) is latency-serialized at ~556us. New structure:
//   attnA: block=(head, 64-q-tile), 1024 blk x 256 thr (4 blk/CU), SINGLE-pass
//          online softmax, zero main-loop barriers (wave-private P transpose;
//          cross-lane max via 4 shfl_xor). Writes O(head), Q(scaled bf16),
//          stats(m,1/l), diag -> d_ws.
//   attnB: PSA = sum_h wvh*softmax_h as GEMM-shaped kernel over (q64,k64,b)
//          tiles, 2048 blocks; recomputes QK from Qbuf with final stats.
//   gemm_nt_f32: out = Obuf @ wo^T (f32 store)
//   gemm_nn_add: out += PSA @ x (verified in v13)
// ws layout: PSA 16M @0 | Qbuf 8M @16M | Obuf 8M @24M | Sbuf 512K @32M |
//            Dbuf 16K @32.5M  (need ~32.6MB; fallback v13 path, then v9).
#include <hip/hip_runtime.h>

typedef unsigned short u16;
typedef unsigned int   u32;
typedef unsigned char  u8;
typedef __attribute__((ext_vector_type(8))) short          short8;
typedef __attribute__((ext_vector_type(8))) unsigned short ushort8;
typedef __attribute__((ext_vector_type(4))) float          f32x4;

#define MFMA(a,b,c) __builtin_amdgcn_mfma_f32_16x16x32_bf16((a),(b),(c),0,0,0)
#define Nx 2048
#define Dx 1024
#define SCALEx 0.125f
#define L2E 1.4426950408889634f

__device__ __forceinline__ float bf2f(u16 u){ u32 x=((u32)u)<<16; return __builtin_bit_cast(float,x); }
__device__ __forceinline__ u16 f2bf(float f){ u32 u=__builtin_bit_cast(u32,f); u32 r=(u+0x7FFFu+((u>>16)&1u))>>16; return (u16)r; }
__device__ __forceinline__ short8 lds8(const u16* p){ return *(const short8*)p; }

// ---- dtype normalization (identity if already bf16) ----
__device__ int looks_bf16_dev(const u16* p, int nsamp, float lo, float hi){
  int cnt = 0;
  for (int i = 0; i < nsamp; ++i){
    float a = fabsf(bf2f(p[2*i]));
    if (a >= lo && a <= hi) cnt++;
  }
  return (2*cnt > nsamp) ? 1 : 0;
}

__global__ __launch_bounds__(256) void conv_w(const void* __restrict__ in, u16* __restrict__ S,
                                              int n, int nsamp, float lo, float hi){
  __shared__ int flag;
  if (threadIdx.x == 0) flag = looks_bf16_dev((const u16*)in, nsamp, lo, hi);
  __syncthreads();
  const int isbf = flag;
  int i = blockIdx.x*256 + threadIdx.x;
  int stride = gridDim.x*256;
  if (isbf){
    const u16* pu = (const u16*)in;
    for (; i < n; i += stride) S[i] = pu[i];
  } else {
    const float* pf = (const float*)in;
    for (; i < n; i += stride) S[i] = f2bf(pf[i]);
  }
}

__global__ __launch_bounds__(256) void copyb(const u16* __restrict__ S, u16* __restrict__ dst, int n){
  int i = blockIdx.x*256 + threadIdx.x;
  int stride = gridDim.x*256;
  for (; i < n; i += stride) dst[i] = S[i];
}

__global__ void conv_small(void* buf, int n, float lo, float hi){
  __shared__ float tmp[64];
  __shared__ int flag;
  int t = threadIdx.x;
  if (t == 0) flag = looks_bf16_dev((const u16*)buf, n/2, lo, hi);
  __syncthreads();
  if (t < n) tmp[t] = flag ? bf2f(((const u16*)buf)[t]) : ((const float*)buf)[t];
  __syncthreads();
  if (t < n) ((u16*)buf)[t] = f2bf(tmp[t]);
}

// ---------------------------------------------------------------------------
// NT GEMM bf16: C[M][ldc] = A[M][1024] @ Bt[N][1024]^T
// ---------------------------------------------------------------------------
__global__ __launch_bounds__(256) void gemm_bf16(
    const u16* __restrict__ A, const u16* __restrict__ Bt, u16* __restrict__ C, int ldc)
{
  const int tid = threadIdx.x;
  const int lane = tid & 63, wave = tid >> 6;
  const int wm = wave >> 1, wn = wave & 1;
  const int l15 = lane & 15, quad = lane >> 4;
  const int m0 = blockIdx.y * 128, n0 = blockIdx.x * 128;
  __shared__ u16 As[128*32], Bs[128*32];
  f32x4 acc[4][4] = {};
  const int srow0 = tid >> 2, scol = tid & 3;
  const int srow1 = (tid + 256) >> 2;
  for (int k0 = 0; k0 < 1024; k0 += 32) {
    ushort8 a0 = *(const ushort8*)&A [(size_t)(m0 + srow0)*1024 + k0 + scol*8];
    ushort8 b0 = *(const ushort8*)&Bt[(size_t)(n0 + srow0)*1024 + k0 + scol*8];
    ushort8 a1 = *(const ushort8*)&A [(size_t)(m0 + srow1)*1024 + k0 + scol*8];
    ushort8 b1 = *(const ushort8*)&Bt[(size_t)(n0 + srow1)*1024 + k0 + scol*8];
    __syncthreads();
    *(ushort8*)&As[srow0*32 + scol*8] = a0;
    *(ushort8*)&Bs[srow0*32 + scol*8] = b0;
    *(ushort8*)&As[srow1*32 + scol*8] = a1;
    *(ushort8*)&Bs[srow1*32 + scol*8] = b1;
    __syncthreads();
    short8 af[4], bfr[4];
    #pragma unroll
    for (int i = 0; i < 4; ++i) af[i]  = lds8(&As[(wm*64 + i*16 + l15)*32 + quad*8]);
    #pragma unroll
    for (int j = 0; j < 4; ++j) bfr[j] = lds8(&Bs[(wn*64 + j*16 + l15)*32 + quad*8]);
    #pragma unroll
    for (int i = 0; i < 4; ++i)
      #pragma unroll
      for (int j = 0; j < 4; ++j)
        acc[i][j] = MFMA(af[i], bfr[j], acc[i][j]);
  }
  const int q4 = quad*4;
  #pragma unroll
  for (int i = 0; i < 4; ++i)
    #pragma unroll
    for (int j = 0; j < 4; ++j)
      #pragma unroll
      for (int r = 0; r < 4; ++r)
        C[(size_t)(m0 + wm*64 + i*16 + q4 + r)*ldc + n0 + wn*64 + j*16 + l15]
          = f2bf(acc[i][j][r]);
}

// ---------------------------------------------------------------------------
// NT GEMM bf16 -> f32 C: C[M][1024] = A[M][1024] @ Bt[1024][1024]^T
// ---------------------------------------------------------------------------
__global__ __launch_bounds__(256) void gemm_nt_f32(
    const u16* __restrict__ A, const u16* __restrict__ Bt, float* __restrict__ C)
{
  const int tid = threadIdx.x;
  const int lane = tid & 63, wave = tid >> 6;
  const int wm = wave >> 1, wn = wave & 1;
  const int l15 = lane & 15, quad = lane >> 4;
  const int m0 = blockIdx.y * 128, n0 = blockIdx.x * 128;
  __shared__ u16 As[128*32], Bs[128*32];
  f32x4 acc[4][4] = {};
  const int srow0 = tid >> 2, scol = tid & 3;
  const int srow1 = (tid + 256) >> 2;
  for (int k0 = 0; k0 < 1024; k0 += 32) {
    ushort8 a0 = *(const ushort8*)&A [(size_t)(m0 + srow0)*1024 + k0 + scol*8];
    ushort8 b0 = *(const ushort8*)&Bt[(size_t)(n0 + srow0)*1024 + k0 + scol*8];
    ushort8 a1 = *(const ushort8*)&A [(size_t)(m0 + srow1)*1024 + k0 + scol*8];
    ushort8 b1 = *(const ushort8*)&Bt[(size_t)(n0 + srow1)*1024 + k0 + scol*8];
    __syncthreads();
    *(ushort8*)&As[srow0*32 + scol*8] = a0;
    *(ushort8*)&Bs[srow0*32 + scol*8] = b0;
    *(ushort8*)&As[srow1*32 + scol*8] = a1;
    *(ushort8*)&Bs[srow1*32 + scol*8] = b1;
    __syncthreads();
    short8 af[4], bfr[4];
    #pragma unroll
    for (int i = 0; i < 4; ++i) af[i]  = lds8(&As[(wm*64 + i*16 + l15)*32 + quad*8]);
    #pragma unroll
    for (int j = 0; j < 4; ++j) bfr[j] = lds8(&Bs[(wn*64 + j*16 + l15)*32 + quad*8]);
    #pragma unroll
    for (int i = 0; i < 4; ++i)
      #pragma unroll
      for (int j = 0; j < 4; ++j)
        acc[i][j] = MFMA(af[i], bfr[j], acc[i][j]);
  }
  const int q4 = quad*4;
  #pragma unroll
  for (int i = 0; i < 4; ++i)
    #pragma unroll
    for (int j = 0; j < 4; ++j)
      #pragma unroll
      for (int r = 0; r < 4; ++r)
        C[(size_t)(m0 + wm*64 + i*16 + q4 + r)*1024 + n0 + wn*64 + j*16 + l15]
          = acc[i][j][r];
}

// ---------------------------------------------------------------------------
// NN GEMM bf16 with fp32 accumulate-into-C:
// C[M][1024] += A[M][2048] @ B[2048][1024]   (per-batch via blockIdx.z)
// ---------------------------------------------------------------------------
__global__ __launch_bounds__(256) void gemm_nn_add(
    const u16* __restrict__ A0, const u16* __restrict__ B0, float* __restrict__ C0)
{
  const int tid = threadIdx.x;
  const int lane = tid & 63, wave = tid >> 6;
  const int wm = wave >> 1, wn = wave & 1;
  const int l15 = lane & 15, quad = lane >> 4;
  const int m0 = blockIdx.y * 128, n0 = blockIdx.x * 128;
  const u16* A = A0 + (size_t)blockIdx.z * Nx * Nx;
  const u16* B = B0 + (size_t)blockIdx.z * Nx * Dx;
  float*     C = C0 + (size_t)blockIdx.z * Nx * Dx;
  __shared__ u16 As[128*32];
  __shared__ u16 Bs[128*40];
  f32x4 acc[4][4] = {};
  const int srow0 = tid >> 2, scol = tid & 3;
  const int srow1 = (tid + 256) >> 2;
  const int kp  = tid >> 4;
  const int nc8 = (tid & 15) * 8;
  for (int k0 = 0; k0 < Nx; k0 += 32) {
    ushort8 a0 = *(const ushort8*)&A[(size_t)(m0 + srow0)*Nx + k0 + scol*8];
    ushort8 a1 = *(const ushort8*)&A[(size_t)(m0 + srow1)*Nx + k0 + scol*8];
    ushort8 b0 = *(const ushort8*)&B[(size_t)(k0 + 2*kp    )*Dx + n0 + nc8];
    ushort8 b1 = *(const ushort8*)&B[(size_t)(k0 + 2*kp + 1)*Dx + n0 + nc8];
    __syncthreads();
    *(ushort8*)&As[srow0*32 + scol*8] = a0;
    *(ushort8*)&As[srow1*32 + scol*8] = a1;
    #pragma unroll
    for (int j = 0; j < 8; ++j){
      int n = nc8 + j;
      int slot = kp ^ (((n >> 3) & 3) << 2);
      *(u32*)&Bs[n*40 + slot*2] = (u32)(u16)b0[j] | ((u32)(u16)b1[j] << 16);
    }
    __syncthreads();
    short8 af[4], bfr[4];
    #pragma unroll
    for (int i = 0; i < 4; ++i) af[i] = lds8(&As[(wm*64 + i*16 + l15)*32 + quad*8]);
    #pragma unroll
    for (int j = 0; j < 4; ++j){
      int n = wn*64 + j*16 + l15;
      int q2 = quad ^ ((n >> 3) & 3);
      bfr[j] = lds8(&Bs[n*40 + q2*8]);
    }
    #pragma unroll
    for (int i = 0; i < 4; ++i)
      #pragma unroll
      for (int j = 0; j < 4; ++j)
        acc[i][j] = MFMA(af[i], bfr[j], acc[i][j]);
  }
  const int q4 = quad*4;
  #pragma unroll
  for (int i = 0; i < 4; ++i)
    #pragma unroll
    for (int j = 0; j < 4; ++j)
      #pragma unroll
      for (int r = 0; r < 4; ++r){
        size_t idx = (size_t)(m0 + wm*64 + i*16 + q4 + r)*Dx + n0 + wn*64 + j*16 + l15;
        C[idx] += acc[i][j][r];
      }
}

// ---------------------------------------------------------------------------
// attnA: single-pass flash per (head, 64-row q-tile). 1024 blocks x 256 thr.
// No main-loop barriers. Outputs: Obuf (per-head O, bf16), Qbuf (scaled Q),
// Sbuf (m, 1/l per row x head), Dbuf (exact diag of x x^T).
// ---------------------------------------------------------------------------
__global__ __launch_bounds__(256, 4) void attnA(
    const u16* __restrict__ x, const u16* __restrict__ wq,
    const u16* __restrict__ wkwq, const u16* __restrict__ K16,
    const u16* __restrict__ Vb0, const u16* __restrict__ Vb1a,
    const u16* __restrict__ Vb1b, const u16* __restrict__ xxt,
    u16* __restrict__ Qbuf, u16* __restrict__ Obuf,
    float* __restrict__ Sbuf, float* __restrict__ Dbuf)
{
  __shared__ __align__(16) u8 AR[14592];
  const int tid = threadIdx.x;
  const int lane = tid & 63, w = tid >> 6;
  const int l15 = lane & 15, quad = lane >> 4, q4 = quad*4;
  const int hb = blockIdx.y;                 // 0..31
  const int c = hb & 15, b = hb >> 4;
  const int qt = blockIdx.x;                 // 0..31
  const size_t xbase  = (size_t)b * Nx * Dx;
  const size_t xxbase = (size_t)b * Nx * Nx;
  const int row0 = qt*64 + w*16;             // wave's first q row (batch-local)

  u16*   prtw = (u16*)(AR + 0)    + w*640;   // [16 q][40 keys]
  u16*   qrtw = (u16*)(AR + 5120) + w*1152;  // [16 q][72]
  float* dgv  = (float*)(AR + 14336);        // 64 rows

  // ---- Q prologue: 16 rows x 64 cols of head c, scaled by SCALE*log2e ----
  {
    f32x4 qacc[4] = {};
    #pragma unroll 1
    for (int kc = 0; kc < 32; ++kc) {
      short8 af = *(const short8*)&x[xbase + (size_t)(row0 + l15)*Dx + kc*32 + quad*8];
      #pragma unroll
      for (int j = 0; j < 4; ++j) {
        short8 bf = *(const short8*)&wq[(size_t)(c*64 + j*16 + l15)*Dx + kc*32 + quad*8];
        qacc[j] = MFMA(af, bf, qacc[j]);
      }
    }
    const float qs = SCALEx * L2E;
    #pragma unroll
    for (int j = 0; j < 4; ++j)
      #pragma unroll
      for (int r = 0; r < 4; ++r){
        u16 qv = f2bf(qacc[j][r] * qs);
        qrtw[(q4+r)*72 + j*16 + l15] = qv;
        Qbuf[(size_t)(b*2048 + row0 + q4 + r)*1024 + c*64 + j*16 + l15] = qv;
      }
  }
  short8 qf[2];
  #pragma unroll
  for (int s = 0; s < 2; ++s) qf[s] = lds8(&qrtw[l15*72 + s*32 + quad*8]);

  // ---- exact diag(x x^T) for this block's 64 rows (4 threads/row) ----
  {
    int row = tid >> 2, part = tid & 3;
    float s = 0.f;
    #pragma unroll
    for (int i = 0; i < 32; ++i) {
      short8 v = *(const short8*)&x[xbase + (size_t)(qt*64 + row)*Dx + part*256 + i*8];
      #pragma unroll
      for (int k = 0; k < 8; ++k){ float f = bf2f((u16)v[k]); s += f*f; }
    }
    s += __shfl_xor(s, 1); s += __shfl_xor(s, 2);
    if ((tid & 3) == 0) dgv[row] = s;
  }
  __syncthreads();
  float dv[4];
  #pragma unroll
  for (int r = 0; r < 4; ++r) dv[r] = dgv[w*16 + q4 + r];
  if (c == 0 && tid < 64) Dbuf[b*2048 + qt*64 + tid] = dgv[tid];

  const float wkh = bf2f(wkwq[c]) * L2E;

  // ---- single pass over keys: online softmax + PV ----
  f32x4 O[4] = {};
  float mrun[4], lrun[4];
  #pragma unroll
  for (int r = 0; r < 4; ++r){ mrun[r] = -1e30f; lrun[r] = 0.f; }

  const u16* pk  = K16 + xbase + (size_t)l15*Dx + c*64;
  const u16* pxx = xxt + xxbase + (size_t)(row0 + q4)*Nx + l15;
  const u16* vbp; int dof;
  if (b == 0){ vbp = Vb0; dof = 0; }
  else if (c < 8){ vbp = Vb1a; dof = 0; }
  else { vbp = Vb1b; dof = 512; }
  const u16* pv = vbp + (size_t)(c*64 - dof + l15)*Nx;

  #pragma unroll 1
  for (int mt = 0; mt < 64; ++mt) {
    float xb[2][4];
    #pragma unroll
    for (int s = 0; s < 2; ++s)
      #pragma unroll
      for (int r = 0; r < 4; ++r)
        xb[s][r] = bf2f(pxx[r*Nx + s*16]);
    short8 kf[2][2];
    #pragma unroll
    for (int s = 0; s < 2; ++s)
      #pragma unroll
      for (int k2 = 0; k2 < 2; ++k2)
        kf[s][k2] = *(const short8*)&pk[s*16*Dx + k2*32 + quad*8];
    short8 vf[4];
    #pragma unroll
    for (int dt = 0; dt < 4; ++dt)
      vf[dt] = *(const short8*)&pv[dt*16*Nx + quad*8];
    f32x4 t2[2];
    #pragma unroll
    for (int s = 0; s < 2; ++s){
      f32x4 t = {};
      t = MFMA(qf[0], kf[s][0], t);
      t = MFMA(qf[1], kf[s][1], t);
      t2[s] = t;
    }
    const int kb = mt*32 + l15;
    float sc[4];
    #pragma unroll
    for (int r = 0; r < 4; ++r){
      const int ng = row0 + q4 + r;
      float b0 = (kb      == ng) ? dv[r] : xb[0][r];
      float b1 = (kb + 16 == ng) ? dv[r] : xb[1][r];
      float sv0 = t2[0][r] + wkh*b0;
      float sv1 = t2[1][r] + wkh*b1;
      float mx = fmaxf(sv0, sv1);
      mx = fmaxf(mx, __shfl_xor(mx, 1));
      mx = fmaxf(mx, __shfl_xor(mx, 2));
      mx = fmaxf(mx, __shfl_xor(mx, 4));
      mx = fmaxf(mx, __shfl_xor(mx, 8));       // consistent across 16 l15 lanes
      float mn = fmaxf(mrun[r], mx);
      float scr = exp2f(mrun[r] - mn);
      float e0 = exp2f(sv0 - mn);
      float e1 = exp2f(sv1 - mn);
      lrun[r] = lrun[r]*scr + e0 + e1;
      mrun[r] = mn;
      sc[r] = scr;
      prtw[(q4+r)*40 + l15]      = f2bf(e0);
      prtw[(q4+r)*40 + 16 + l15] = f2bf(e1);
    }
    #pragma unroll
    for (int dt = 0; dt < 4; ++dt)
      #pragma unroll
      for (int r = 0; r < 4; ++r)
        O[dt][r] *= sc[r];
    short8 pf = lds8(&prtw[l15*40 + quad*8]);
    #pragma unroll
    for (int dt = 0; dt < 4; ++dt) O[dt] = MFMA(pf, vf[dt], O[dt]);
    pk += 32*Dx; pxx += 32; pv += 32;
  }

  // ---- finish: cross-lane l sum, normalize, store O + stats ----
  float il[4];
  #pragma unroll
  for (int r = 0; r < 4; ++r){
    float l = lrun[r];
    l += __shfl_xor(l, 1); l += __shfl_xor(l, 2);
    l += __shfl_xor(l, 4); l += __shfl_xor(l, 8);
    il[r] = 1.0f / fmaxf(l, 1e-30f);
  }
  #pragma unroll
  for (int dt = 0; dt < 4; ++dt)
    #pragma unroll
    for (int r = 0; r < 4; ++r)
      Obuf[(size_t)(b*2048 + row0 + q4 + r)*1024 + c*64 + dt*16 + l15]
        = f2bf(O[dt][r] * il[r]);
  if (l15 == 0){
    #pragma unroll
    for (int r = 0; r < 4; ++r){
      size_t si = ((size_t)(b*2048 + row0 + q4 + r)*16 + c)*2;
      Sbuf[si + 0] = mrun[r];
      Sbuf[si + 1] = il[r];
    }
  }
}

// ---------------------------------------------------------------------------
// attnB: PSA[b][q][k] = sum_h wvh * exp2(sv_h - m_h) * il_h over 64x64 tiles.
// 2048 blocks x 256 thr. QK recomputed from Qbuf; stats from Sbuf.
// ---------------------------------------------------------------------------
__global__ __launch_bounds__(256, 4) void attnB(
    const u16* __restrict__ Qbuf, const u16* __restrict__ K16,
    const u16* __restrict__ wkwq, const u16* __restrict__ wvwo,
    const u16* __restrict__ xxt, const float* __restrict__ Sbuf,
    const float* __restrict__ Dbuf, u16* __restrict__ PSA)
{
  __shared__ float sst[2048];                // [64 rows][16 h][2]
  const int tid = threadIdx.x;
  const int lane = tid & 63, w = tid >> 6;
  const int l15 = lane & 15, quad = lane >> 4, q4 = quad*4;
  const int kt = blockIdx.x, qt = blockIdx.y, b = blockIdx.z;
  const size_t xbase  = (size_t)b * Nx * Dx;
  const size_t xxbase = (size_t)b * Nx * Nx;

  {
    const float* src = Sbuf + ((size_t)b*2048 + qt*64)*32;
    for (int i = tid; i < 2048; i += 256) sst[i] = src[i];
  }
  __syncthreads();

  const int rloc = w*16 + q4;                // + r: block-local row
  float xbv[4][4];                           // [ks][r] bias values
  #pragma unroll
  for (int ks = 0; ks < 4; ++ks)
    #pragma unroll
    for (int r = 0; r < 4; ++r){
      int gr = qt*64 + rloc + r;
      int gc = kt*64 + ks*16 + l15;
      float v = bf2f(xxt[xxbase + (size_t)gr*Nx + gc]);
      if (gr == gc) v = Dbuf[b*2048 + gr];
      xbv[ks][r] = v;
    }

  f32x4 psa_[4] = {};
  #pragma unroll 1
  for (int h = 0; h < 16; ++h){
    const float wkh = bf2f(wkwq[h]) * L2E;
    const float wvh = bf2f(wvwo[h]);
    short8 qf[2];
    #pragma unroll
    for (int s = 0; s < 2; ++s)
      qf[s] = *(const short8*)&Qbuf[(size_t)(b*2048 + qt*64 + w*16 + l15)*1024 + h*64 + s*32 + quad*8];
    short8 kf[4][2];
    #pragma unroll
    for (int ks = 0; ks < 4; ++ks)
      #pragma unroll
      for (int k2 = 0; k2 < 2; ++k2)
        kf[ks][k2] = *(const short8*)&K16[xbase + (size_t)(kt*64 + ks*16 + l15)*Dx + h*64 + k2*32 + quad*8];
    #pragma unroll
    for (int ks = 0; ks < 4; ++ks){
      f32x4 t = {};
      t = MFMA(qf[0], kf[ks][0], t);
      t = MFMA(qf[1], kf[ks][1], t);
      #pragma unroll
      for (int r = 0; r < 4; ++r){
        float m   = sst[((rloc + r)*16 + h)*2 + 0];
        float ilw = sst[((rloc + r)*16 + h)*2 + 1] * wvh;
        float sv = t[r] + wkh*xbv[ks][r];
        psa_[ks][r] += exp2f(fminf(sv - m, 0.f)) * ilw;
      }
    }
  }
  #pragma unroll
  for (int ks = 0; ks < 4; ++ks)
    #pragma unroll
    for (int r = 0; r < 4; ++r)
      PSA[(size_t)(b*2048 + qt*64 + rloc + r)*Nx + kt*64 + ks*16 + l15]
        = f2bf(psa_[ks][r]);
}

// ---------------------------------------------------------------------------
// attn2 (v13 path, verified) — used if ws in [16MB, 33MB)
// ---------------------------------------------------------------------------
#define B_PRT 0
#define B_PSP 20480
#define B_DG  61440
#define B_SZ  86016

__global__ __launch_bounds__(1024)
__attribute__((amdgpu_waves_per_eu(4, 4)))
void attn2(
    const u16* __restrict__ x, const u16* __restrict__ wq,
    const u16* __restrict__ wo, const u16* __restrict__ wkwq,
    const u16* __restrict__ wvwo, const u16* __restrict__ K16,
    const u16* __restrict__ Vb0, const u16* __restrict__ Vb1a,
    const u16* __restrict__ Vb1b, u16* __restrict__ PSA,
    float* out)
{
  __shared__ __align__(16) u8 AR[B_SZ];
  const int tid = threadIdx.x;
  const int lane = tid & 63, c = tid >> 6;
  const int l15 = lane & 15, quad = lane >> 4, q4 = quad*4;
  int bb = blockIdx.x; bb = (bb & 7)*32 + (bb >> 3);
  const int b = bb >> 7, n0 = (bb & 127) * 16;
  const size_t xbase = (size_t)b * Nx * Dx;
  const u16* xxt = (const u16*)out;
  const size_t xxbase = (size_t)b * Nx * Nx;
  u16* psag = PSA + (size_t)b * Nx * Nx;

  u16*   prt = (u16*)(AR + B_PRT);
  u16*   psp = (u16*)(AR + B_PSP);
  float* dgv = (float*)(AR + B_DG);
  u16*   qrt = (u16*)(AR + 0) + c*(16*72);

  {
    f32x4 qacc[4] = {};
    #pragma unroll 1
    for (int kc = 0; kc < 32; ++kc) {
      short8 af = *(const short8*)&x[xbase + (size_t)(n0 + l15)*Dx + kc*32 + quad*8];
      #pragma unroll
      for (int j = 0; j < 4; ++j) {
        short8 bf = *(const short8*)&wq[(size_t)(c*64 + j*16 + l15)*Dx + kc*32 + quad*8];
        qacc[j] = MFMA(af, bf, qacc[j]);
      }
    }
    const float qs = SCALEx * L2E;
    #pragma unroll
    for (int j = 0; j < 4; ++j)
      #pragma unroll
      for (int r = 0; r < 4; ++r)
        qrt[(q4+r)*72 + j*16 + l15] = f2bf(qacc[j][r] * qs);
  }
  {
    float s = 0.f;
    #pragma unroll
    for (int p = 0; p < 2; ++p) {
      short8 v = *(const short8*)&x[xbase + (size_t)(n0+c)*Dx + p*512 + lane*8];
      #pragma unroll
      for (int i = 0; i < 8; ++i){ float f = bf2f((u16)v[i]); s += f*f; }
    }
    #pragma unroll
    for (int o = 1; o < 64; o <<= 1) s += __shfl_xor(s, o);
    if (lane == 0) dgv[c] = s;
  }
  short8 qf[2];
  #pragma unroll
  for (int s = 0; s < 2; ++s) qf[s] = lds8(&qrt[l15*72 + s*32 + quad*8]);
  __syncthreads();
  float dv[4];
  #pragma unroll
  for (int r = 0; r < 4; ++r) dv[r] = dgv[q4+r];
  __syncthreads();

  const float wkh = bf2f(wkwq[c]) * L2E;
  const float wvh = bf2f(wvwo[c]);

  float mrun[4], lrun[4];
  #pragma unroll
  for (int r = 0; r < 4; ++r){ mrun[r] = -1e30f; lrun[r] = 0.f; }

  const u16* pk  = K16 + xbase + (size_t)l15*Dx + c*64;
  const u16* pxx = xxt + xxbase + (size_t)(n0+q4)*Nx + l15;

  #pragma unroll 2
  for (int mt = 0; mt < 64; ++mt) {
    float xb[2][4];
    #pragma unroll
    for (int s = 0; s < 2; ++s)
      #pragma unroll
      for (int r = 0; r < 4; ++r)
        xb[s][r] = bf2f(pxx[r*Nx + s*16]);
    short8 kf[2][2];
    #pragma unroll
    for (int s = 0; s < 2; ++s)
      #pragma unroll
      for (int k2 = 0; k2 < 2; ++k2)
        kf[s][k2] = *(const short8*)&pk[s*16*Dx + k2*32 + quad*8];
    f32x4 t2[2];
    #pragma unroll
    for (int s = 0; s < 2; ++s){
      f32x4 t = {};
      t = MFMA(qf[0], kf[s][0], t);
      t = MFMA(qf[1], kf[s][1], t);
      t2[s] = t;
    }
    const int kb = mt*32 + l15;
    #pragma unroll
    for (int r = 0; r < 4; ++r){
      const int ng = n0 + q4 + r;
      float b0 = (kb      == ng) ? dv[r] : xb[0][r];
      float b1 = (kb + 16 == ng) ? dv[r] : xb[1][r];
      float sv0 = t2[0][r] + wkh*b0;
      float sv1 = t2[1][r] + wkh*b1;
      float m2 = fmaxf(sv0, sv1);
      float mn = fmaxf(mrun[r], m2);
      lrun[r] = lrun[r]*exp2f(mrun[r]-mn) + exp2f(sv0-mn) + exp2f(sv1-mn);
      mrun[r] = mn;
    }
    pk += 32*Dx; pxx += 32;
  }
  float ms[4], il[4];
  #pragma unroll
  for (int r = 0; r < 4; ++r){
    float mr = mrun[r];
    #pragma unroll
    for (int o = 1; o < 16; o <<= 1) mr = fmaxf(mr, __shfl_xor(mr, o));
    float ls = lrun[r]*exp2f(mrun[r]-mr);
    #pragma unroll
    for (int o = 1; o < 16; o <<= 1) ls += __shfl_xor(ls, o);
    ms[r] = mr; il[r] = 1.0f/fmaxf(ls, 1e-30f);
  }

  f32x4 O[4] = {};
  const u16* vbp; int voff;
  if (b == 0){ vbp = Vb0; voff = 0; }
  else if (c < 8){ vbp = Vb1a; voff = 0; }
  else { vbp = Vb1b; voff = 512; }
  const u16* pv = vbp + (size_t)(c*64 - voff + l15)*Nx;
  pk  = K16 + xbase + (size_t)l15*Dx + c*64;
  pxx = xxt + xxbase + (size_t)(n0+q4)*Nx + l15;

  #pragma unroll 1
  for (int mt = 0; mt < 64; ++mt) {
    float xb[2][4];
    #pragma unroll
    for (int s = 0; s < 2; ++s)
      #pragma unroll
      for (int r = 0; r < 4; ++r)
        xb[s][r] = bf2f(pxx[r*Nx + s*16]);
    short8 kf[2][2];
    #pragma unroll
    for (int s = 0; s < 2; ++s)
      #pragma unroll
      for (int k2 = 0; k2 < 2; ++k2)
        kf[s][k2] = *(const short8*)&pk[s*16*Dx + k2*32 + quad*8];
    short8 vf[4];
    #pragma unroll
    for (int dt = 0; dt < 4; ++dt)
      vf[dt] = *(const short8*)&pv[dt*16*Nx + quad*8];
    f32x4 t2[2];
    #pragma unroll
    for (int s = 0; s < 2; ++s){
      f32x4 t = {};
      t = MFMA(qf[0], kf[s][0], t);
      t = MFMA(qf[1], kf[s][1], t);
      t2[s] = t;
    }
    const int kb = mt*32 + l15;
    u16* pspw = psp + (mt & 1)*10240;
    #pragma unroll
    for (int s = 0; s < 2; ++s)
      #pragma unroll
      for (int r = 0; r < 4; ++r){
        const int ng = n0 + q4 + r;
        float bias = (kb + s*16 == ng) ? dv[r] : xb[s][r];
        float sv = t2[s][r] + wkh*bias;
        float p = exp2f(fminf(sv - ms[r], 0.f)) * il[r];
        prt[c*640 + (q4+r)*40 + s*16 + l15] = f2bf(p);
        pspw[c*640 + (q4+r)*40 + s*16 + l15] = f2bf(wvh * p);
      }
    short8 pf = lds8(&prt[c*640 + l15*40 + quad*8]);
    #pragma unroll
    for (int dt = 0; dt < 4; ++dt) O[dt] = MFMA(pf, vf[dt], O[dt]);
    __syncthreads();
    if (tid < 512){
      const int qq = tid >> 5, mm = tid & 31;
      float v = 0.f;
      #pragma unroll
      for (int w = 0; w < 16; ++w) v += bf2f(pspw[w*640 + qq*40 + mm]);
      psag[(size_t)(n0 + qq)*Nx + mt*32 + mm] = f2bf(v);
    }
    pk += 32*Dx; pxx += 32; pv += 32;
  }

  __syncthreads();
  u16* ol = (u16*)(AR + 0);
  #pragma unroll
  for (int dt = 0; dt < 4; ++dt)
    #pragma unroll
    for (int r = 0; r < 4; ++r)
      ol[(q4+r)*1040 + c*64 + dt*16 + l15] = f2bf(O[dt][r]);
  __syncthreads();
  f32x4 Uo[4] = {};
  #pragma unroll 1
  for (int kc = 0; kc < 32; ++kc){
    short8 af = lds8(&ol[l15*1040 + kc*32 + quad*8]);
    #pragma unroll
    for (int ct = 0; ct < 4; ++ct){
      short8 bw = *(const short8*)&wo[(size_t)(c*64 + ct*16 + l15)*Dx + kc*32 + quad*8];
      Uo[ct] = MFMA(af, bw, Uo[ct]);
    }
  }
  #pragma unroll
  for (int ct = 0; ct < 4; ++ct)
    #pragma unroll
    for (int r = 0; r < 4; ++r)
      out[xbase + (size_t)(n0+q4+r)*Dx + c*64 + ct*16 + l15] = Uo[ct][r];
}

// ---------------------------------------------------------------------------
extern "C" void kernel_launch(void* const* d_in, const int* in_sizes, int n_in,
                              void* d_out, int out_size, void* d_ws, size_t ws_size,
                              hipStream_t stream) {
  u16* x16   = (u16*)d_in[0];
  u16* K16   = x16 + 4u*1024u*1024u;
  u16* wqk16 = (u16*)d_in[1];
  u16* Vb0   = wqk16 + 2u*1024u*1024u;
  u16* wv16  = (u16*)d_in[2];
  u16* Vb1a  = wv16 + 1024u*1024u;
  u16* wo16  = (u16*)d_in[3];
  u16* Vb1b  = wo16 + 1024u*1024u;
  float* outF = (float*)d_out;
  u16* S = (u16*)d_out;

  const float loW = 0.000244140625f, hiW = 0.25f;
  conv_w<<<dim3(512), 256, 0, stream>>>(d_in[0], S, 4*1024*1024, 512, 0.00390625f, 16.0f);
  copyb <<<dim3(512), 256, 0, stream>>>(S, x16, 4*1024*1024);
  conv_w<<<dim3(256), 256, 0, stream>>>(d_in[1], S, 2*1024*1024, 512, loW, hiW);
  copyb <<<dim3(256), 256, 0, stream>>>(S, wqk16, 2*1024*1024);
  conv_w<<<dim3(128), 256, 0, stream>>>(d_in[2], S, 1024*1024, 512, loW, hiW);
  copyb <<<dim3(128), 256, 0, stream>>>(S, wv16, 1024*1024);
  conv_w<<<dim3(128), 256, 0, stream>>>(d_in[3], S, 1024*1024, 512, loW, hiW);
  copyb <<<dim3(128), 256, 0, stream>>>(S, wo16, 1024*1024);
  conv_small<<<dim3(1), 64, 0, stream>>>((void*)d_in[4], 16, loW, hiW);
  conv_small<<<dim3(1), 64, 0, stream>>>((void*)d_in[5], 16, loW, hiW);

  // ws layout (bytes)
  const size_t OFF_PSA = 0;
  const size_t OFF_Q   = 16777216;
  const size_t OFF_O   = 25165824;
  const size_t OFF_S   = 33554432;
  const size_t OFF_D   = 34078720;
  const size_t NEED    = 34095104;

  // K = x @ wk^T (both batches)
  gemm_bf16<<<dim3(8, 32), 256, 0, stream>>>(x16, wqk16 + 1024u*1024u, K16, 1024);
  // V^T = wv @ x^T
  gemm_bf16<<<dim3(16, 8), 256, 0, stream>>>(wv16, x16, Vb0, 2048);
  gemm_bf16<<<dim3(16, 4), 256, 0, stream>>>(wv16,              x16 + 2048u*1024u, Vb1a, 2048);
  gemm_bf16<<<dim3(16, 4), 256, 0, stream>>>(wv16 + 512u*1024u, x16 + 2048u*1024u, Vb1b, 2048);
  // XXT = x @ x^T (bf16) into d_out
  gemm_bf16<<<dim3(16, 16), 256, 0, stream>>>(x16,               x16,               (u16*)d_out,                  2048);
  gemm_bf16<<<dim3(16, 16), 256, 0, stream>>>(x16 + 2048u*1024u, x16 + 2048u*1024u, (u16*)d_out + 4u*1024u*1024u, 2048);

  if (d_ws != nullptr && ws_size >= NEED) {
    u8* ws = (u8*)d_ws;
    attnA<<<dim3(32, 32), 256, 0, stream>>>(
        x16, wqk16, (const u16*)d_in[4], K16, Vb0, Vb1a, Vb1b, (const u16*)d_out,
        (u16*)(ws + OFF_Q), (u16*)(ws + OFF_O),
        (float*)(ws + OFF_S), (float*)(ws + OFF_D));
    attnB<<<dim3(32, 32, 2), 256, 0, stream>>>(
        (const u16*)(ws + OFF_Q), K16, (const u16*)d_in[4], (const u16*)d_in[5],
        (const u16*)d_out, (const float*)(ws + OFF_S), (const float*)(ws + OFF_D),
        (u16*)(ws + OFF_PSA));
    gemm_nt_f32<<<dim3(8, 32), 256, 0, stream>>>((const u16*)(ws + OFF_O), wo16, outF);
    gemm_nn_add<<<dim3(8, 16, 2), 256, 0, stream>>>((const u16*)(ws + OFF_PSA), x16, outF);
  } else if (d_ws != nullptr && ws_size >= (size_t)2*2048*2048*2) {
    attn2<<<dim3(256), 1024, 0, stream>>>(x16, wqk16, wo16,
        (const u16*)d_in[4], (const u16*)d_in[5], K16, Vb0, Vb1a, Vb1b,
        (u16*)d_ws, outF);
    gemm_nn_add<<<dim3(8, 16, 2), 256, 0, stream>>>((const u16*)d_ws, x16, outF);
  }
}